// Round 13
// baseline (705.300 us; speedup 1.0000x reference)
//
#include <hip/hip_runtime.h>

// ---------------------------------------------------------------------------
// Pointer-generator decoder. B=32 S=400 H=512 E=300 Vs=200 T=32 EN=50000 V=50200
// Round 13: r12 with the gemm_v staging bug fixed — each thread loads BOTH an
// A and a B uint4 (full 256x32 tiles; r12 only filled half of each -> NaN).
// ---------------------------------------------------------------------------

typedef __attribute__((ext_vector_type(8))) short short8;
typedef __attribute__((ext_vector_type(4))) float f32x4;
typedef unsigned short us;

#define SCW (-2.8853900817779268f)  // -2*log2(e)

__device__ __forceinline__ float bf2f(us u) {
  return __uint_as_float(((unsigned)u) << 16);
}
__device__ __forceinline__ us f2bf(float f) {
  unsigned x = __float_as_uint(f);
  unsigned r = x + 0x7fffu + ((x >> 16) & 1u);
  return (us)(r >> 16);
}
__device__ __forceinline__ float fsigmoid(float x) { return 1.f / (1.f + __expf(-x)); }
__device__ __forceinline__ float ftanh(float x) {
  float t = __expf(-2.f * fabsf(x));
  float r = (1.f - t) / (1.f + t);
  return x >= 0.f ? r : -r;
}
__device__ __forceinline__ float ftanh_fast(float x) {
  float u = exp2f(SCW * fabsf(x));
  float r = (1.f - u) * __builtin_amdgcn_rcpf(1.f + u);
  return copysignf(r, x);
}
__device__ __forceinline__ void unpack8(uint4 v, float* f) {
  f[0] = bf2f((us)(v.x & 0xffff)); f[1] = bf2f((us)(v.x >> 16));
  f[2] = bf2f((us)(v.y & 0xffff)); f[3] = bf2f((us)(v.y >> 16));
  f[4] = bf2f((us)(v.z & 0xffff)); f[5] = bf2f((us)(v.z >> 16));
  f[6] = bf2f((us)(v.w & 0xffff)); f[7] = bf2f((us)(v.w >> 16));
}

// --------------------------- merged precompute kernel ----------------------
struct PP {
  const float *enc, *hidden0, *Wk_c, *Wk_u, *Wq_c, *Wq_u, *Wc, *W_ih, *W_hh, *W_embed;
  const int *tgt, *sv;
  us *encb, *hball, *WkcT, *WkuT, *WqcuT, *WcT, *WihT, *WhhF, *xe, *uve;
};

__device__ void tcast_job(const float* __restrict__ src, us* __restrict__ dst,
                          int R, int C, int Rpad, int x, int y, float scale,
                          int lt, float* tb) {
  int tx = lt & 31, ty = lt >> 5;
  int c0 = x * 32, r0 = y * 32;
#pragma unroll
  for (int i = 0; i < 4; ++i) {
    int r = r0 + ty + i * 8, c = c0 + tx;
    tb[(ty + i * 8) * 33 + tx] = (r < R && c < C) ? src[(size_t)r * C + c] : 0.f;
  }
  __syncthreads();
#pragma unroll
  for (int i = 0; i < 4; ++i) {
    int c = c0 + ty + i * 8, rr = r0 + tx;
    if (c < C && rr < Rpad)
      dst[(size_t)c * Rpad + rr] = f2bf(scale * tb[tx * 33 + ty + i * 8]);
  }
}

__global__ __launch_bounds__(256) void k_prep(PP P) {
  __shared__ float tb[32 * 33];
  const int bid = blockIdx.x, tid = threadIdx.x;
  if (bid < 1024) {
    for (int i = bid * 256 + tid; i < 3276800; i += 1024 * 256) {
      float4 v = ((const float4*)P.enc)[i];
      ushort4 o;
      o.x = f2bf(v.x); o.y = f2bf(v.y); o.z = f2bf(v.z); o.w = f2bf(v.w);
      ((ushort4*)P.encb)[i] = o;
    }
  } else if (bid < 1040) {
    int i = (bid - 1024) * 256 + tid;
    float4 v = ((const float4*)P.hidden0)[i];
    ushort4 o;
    o.x = f2bf(v.x); o.y = f2bf(v.y); o.z = f2bf(v.z); o.w = f2bf(v.w);
    ((ushort4*)P.hball)[i] = o;
  } else if (bid < 1552) {
    int j = bid - 1040;
    tcast_job(P.Wk_c, P.WkcT, 1024, 512, 1024, j & 15, j >> 4, SCW, tid, tb);
  } else if (bid < 1712) {
    int j = bid - 1552;
    tcast_job(P.Wk_u, P.WkuT, 300, 512, 320, j % 16, j / 16, SCW, tid, tb);
  } else if (bid < 1968) {
    int j = bid - 1712;
    tcast_job(P.Wq_c, P.WqcuT, 512, 512, 512, j & 15, j >> 4, SCW, tid, tb);
  } else if (bid < 2224) {
    int j = bid - 1968;
    tcast_job(P.Wq_u, P.WqcuT + 512ull * 512, 512, 512, 512, j & 15, j >> 4, SCW, tid, tb);
  } else if (bid < 3296) {
    int j = bid - 2224;
    tcast_job(P.Wc, P.WcT, 2136, 512, 2144, j % 16, j / 16, 1.f, tid, tb);
  } else if (bid < 3680) {
    int row = (bid - 3296) * 4 + (tid >> 6), k = tid & 63;
    for (int kk = k; kk < 320; kk += 64)
      P.WihT[(size_t)row * 320 + kk] =
          (kk < 300) ? f2bf(P.W_ih[(size_t)row * 300 + kk]) : (us)0;
  } else if (bid < 4064) {
    int job = (bid - 3680) * 4 + (tid >> 6), l = tid & 63;
    int q = job / 192, rem = job - q * 192, lt2 = rem >> 4, kt = rem & 15;
    int localrow = lt2 * 16 + (l & 15);
    int g = localrow >> 6, jj = localrow & 63;
    const float* src =
        P.W_hh + (size_t)(g * 512 + q * 64 + jj) * 512 + kt * 32 + (l >> 4) * 8;
    us* dst = P.WhhF + (((size_t)(q * 12 + lt2) * 16 + kt) * 64 + l) * 8;
#pragma unroll
    for (int i = 0; i < 8; ++i) dst[i] = f2bf(src[i]);
  } else if (bid < 4320) {
    int r = (bid - 4064) * 4 + (tid >> 6), k = tid & 63;
    int t = r >> 5, b = r & 31;
    int tok = (t == 0) ? 1 : P.tgt[b * 32 + (t - 1)];
    const float* src = P.W_embed + (size_t)tok * 300;
    for (int kk = k; kk < 320; kk += 64)
      P.xe[(size_t)r * 320 + kk] = (kk < 300) ? f2bf(src[kk]) : (us)0;
  } else {
    int row = (bid - 4320) * 4 + (tid >> 6), k = tid & 63;
    int tok = P.sv[row];
    const float* src = P.W_embed + (size_t)tok * 300;
    for (int kk = k; kk < 320; kk += 64)
      P.uve[(size_t)row * 320 + kk] = (kk < 300) ? f2bf(src[kk]) : (us)0;
  }
}

// fallback-only transposes
__global__ __launch_bounds__(256) void k_tcastX(const float* __restrict__ src0,
                                                us* __restrict__ dst0,
                                                int R, int C, int Rpad,
                                                size_t srcB, size_t dstB) {
  __shared__ float tile[32 * 33];
  const float* src = src0 + (size_t)blockIdx.z * srcB;
  us* dst = dst0 + (size_t)blockIdx.z * dstB;
  tcast_job(src, dst, R, C, Rpad, blockIdx.x, blockIdx.y, 1.f, threadIdx.x, tile);
}
__global__ __launch_bounds__(256) void k_tcastXb(const us* __restrict__ src0,
                                                 us* __restrict__ dst0,
                                                 int R, int C, int Rpad,
                                                 size_t srcB, size_t dstB) {
  __shared__ us tile[32][33];
  const us* src = src0 + (size_t)blockIdx.z * srcB;
  us* dst = dst0 + (size_t)blockIdx.z * dstB;
  int c0 = blockIdx.x * 32, r0 = blockIdx.y * 32;
  int tx = threadIdx.x & 31, ty = threadIdx.x >> 5;
#pragma unroll
  for (int i = 0; i < 4; ++i) {
    int r = r0 + ty + i * 8, c = c0 + tx;
    tile[ty + i * 8][tx] = (r < R && c < C) ? src[(size_t)r * C + c] : (us)0;
  }
  __syncthreads();
#pragma unroll
  for (int i = 0; i < 4; ++i) {
    int c = c0 + ty + i * 8, rr = r0 + tx;
    if (c < C && rr < Rpad) dst[(size_t)c * Rpad + rr] = tile[tx][ty + i * 8];
  }
}

// --------------------------- big MFMA GEMM (reg-staged) --------------------
// Used for fallback pkc/pku (MODE 0) and fallback vocab (MODE 1, N-major).
template <int MODE, bool NM = false>
__global__ __launch_bounds__(512) void gemm_bt(const us* __restrict__ A,
                                               const us* __restrict__ BT,
                                               int M, int N, int K, int Ntiles,
                                               const float* __restrict__ bias,
                                               float bscale,
                                               us* __restrict__ outB,
                                               float* __restrict__ outF,
                                               float* __restrict__ rowsum) {
  __shared__ us sh[12288];
  __shared__ float rs[256];
  us* As = sh;
  us* Bs = sh + 8192;
  const int tid = threadIdx.x;
  const int lane = tid & 63, wid = tid >> 6;
  const int wr = wid >> 1, wc = wid & 1;
  const int bx = blockIdx.x;
  int mt, nt;
  if (NM) { mt = bx & 3; nt = bx >> 2; }
  else { mt = bx / Ntiles; nt = bx - mt * Ntiles; }
  const int m0 = mt * 256, n0 = nt * 128;
  f32x4 acc[4][4] = {};
  for (int kk = 0; kk < K; kk += 32) {
    uint4 av0, av1, bv;
    {
      int c = tid, row = c >> 2, c8 = (c & 3) * 8;
      av0 = *(const uint4*)(A + (size_t)(m0 + row) * K + kk + c8);
      c = tid + 512; row = c >> 2; c8 = (c & 3) * 8;
      av1 = *(const uint4*)(A + (size_t)(m0 + row) * K + kk + c8);
      c = tid; row = c >> 2; c8 = (c & 3) * 8;
      int nr = n0 + row; if (nr > N - 1) nr = N - 1;
      bv = *(const uint4*)(BT + (size_t)nr * K + kk + c8);
    }
    __syncthreads();
    ((uint4*)As)[tid] = av0;
    ((uint4*)As)[tid + 512] = av1;
    ((uint4*)Bs)[tid] = bv;
    __syncthreads();
    short8 af[4], bfr[4];
#pragma unroll
    for (int m = 0; m < 4; ++m)
      af[m] = *(const short8*)(As + (wr * 64 + m * 16 + (lane & 15)) * 32 + (lane >> 4) * 8);
#pragma unroll
    for (int n = 0; n < 4; ++n)
      bfr[n] = *(const short8*)(Bs + (wc * 64 + n * 16 + (lane & 15)) * 32 + (lane >> 4) * 8);
#pragma unroll
    for (int m = 0; m < 4; ++m)
#pragma unroll
      for (int n = 0; n < 4; ++n)
        acc[m][n] = __builtin_amdgcn_mfma_f32_16x16x32_bf16(af[m], bfr[n], acc[m][n], 0, 0, 0);
  }
  if (MODE == 0) {
#pragma unroll
    for (int m = 0; m < 4; ++m)
#pragma unroll
      for (int n = 0; n < 4; ++n)
#pragma unroll
        for (int reg = 0; reg < 4; ++reg) {
          int r = m0 + wr * 64 + m * 16 + (lane >> 4) * 4 + reg;
          int c = n0 + wc * 64 + n * 16 + (lane & 15);
          outB[(size_t)r * N + c] = f2bf(acc[m][n][reg] + bscale * bias[c]);
        }
  } else {
    if (tid < 256) rs[tid] = 0.f;
    __syncthreads();
#pragma unroll
    for (int m = 0; m < 4; ++m) {
#pragma unroll
      for (int reg = 0; reg < 4; ++reg) {
        int rloc = wr * 64 + m * 16 + (lane >> 4) * 4 + reg;
        float s = 0.f;
#pragma unroll
        for (int n = 0; n < 4; ++n) {
          int c = n0 + wc * 64 + n * 16 + (lane & 15);
          float e = (c < N) ? __expf(acc[m][n][reg]) : 0.f;
          if (c < N) {
            int r = m0 + rloc;
            size_t obase = (size_t)((r & 31) * 32 + (r >> 5)) * 50200;
            outF[obase + c] = e;
          }
          s += e;
        }
        s += __shfl_xor(s, 1, 64); s += __shfl_xor(s, 2, 64);
        s += __shfl_xor(s, 4, 64); s += __shfl_xor(s, 8, 64);
        if ((lane & 15) == 0) atomicAdd(&rs[rloc], s);
      }
    }
    __syncthreads();
    if (tid < 256) atomicAdd(&rowsum[m0 + tid], rs[tid]);
  }
}

// --------------------------- vocab GEMM 256x256 ----------------------------
// A = chb [1024][512], BT = WT [50000][512]. 1024 threads, 16 waves (4x4);
// wave (wr2, wc2) owns rows [wr2*64,+64) x cols [wc2*64,+64). N-major blocks.
// Each thread stages ONE A uint4 AND ONE B uint4 (full 256x32 tiles each).
// Epilogue: bf16 exp -> expb[(r&31)*32+(r>>5)][c] via 32KB LDS bounce,
// rowsum atomics.
__global__ __launch_bounds__(1024, 1) void gemm_v(const us* __restrict__ A,
                                                  const us* __restrict__ BT,
                                                  us* __restrict__ outB,
                                                  float* __restrict__ rowsum) {
  __shared__ us shp[16384];  // As = shp[0..8191], Bs = shp[8192..16383]
  __shared__ float rs[256];
  us* As = shp;
  us* Bs = shp + 8192;
  const int tid = threadIdx.x;
  const int lane = tid & 63, wid = tid >> 6;
  const int wr2 = wid >> 2, wc2 = wid & 3;
  const int bx = blockIdx.x;
  const int mt = bx & 3, nt = bx >> 2;
  const int m0 = mt * 256, n0 = nt * 256;
  const int N = 50000;
  const int srow = tid >> 2, sc8 = (tid & 3) * 8;  // staging row in [0,256)
  int bnr = n0 + srow; if (bnr > N - 1) bnr = N - 1;
  f32x4 acc[4][4] = {};
  for (int kk = 0; kk < 512; kk += 32) {
    uint4 av = *(const uint4*)(A + (size_t)(m0 + srow) * 512 + kk + sc8);
    uint4 bv = *(const uint4*)(BT + (size_t)bnr * 512 + kk + sc8);
    __syncthreads();
    ((uint4*)As)[tid] = av;
    ((uint4*)Bs)[tid] = bv;
    __syncthreads();
    short8 af[4], bfr[4];
#pragma unroll
    for (int m = 0; m < 4; ++m)
      af[m] = *(const short8*)(As + (wr2 * 64 + m * 16 + (lane & 15)) * 32 + (lane >> 4) * 8);
#pragma unroll
    for (int n = 0; n < 4; ++n)
      bfr[n] = *(const short8*)(Bs + (wc2 * 64 + n * 16 + (lane & 15)) * 32 + (lane >> 4) * 8);
#pragma unroll
    for (int m = 0; m < 4; ++m)
#pragma unroll
      for (int n = 0; n < 4; ++n)
        acc[m][n] = __builtin_amdgcn_mfma_f32_16x16x32_bf16(af[m], bfr[n], acc[m][n], 0, 0, 0);
  }
  if (tid < 256) rs[tid] = 0.f;
  __syncthreads();  // K-loop frag reads complete; rs zeroed
  for (int g = 0; g < 4; ++g) {
    if (wr2 == g) {
#pragma unroll
      for (int m = 0; m < 4; ++m)
#pragma unroll
        for (int reg = 0; reg < 4; ++reg) {
          int rloc_g = m * 16 + (lane >> 4) * 4 + reg;  // row within 64-group
          float s = 0.f;
#pragma unroll
          for (int n = 0; n < 4; ++n) {
            int c = n0 + wc2 * 64 + n * 16 + (lane & 15);
            float e = (c < N) ? __expf(acc[m][n][reg]) : 0.f;
            shp[rloc_g * 256 + wc2 * 64 + n * 16 + (lane & 15)] = f2bf(e);
            s += e;
          }
          s += __shfl_xor(s, 1, 64); s += __shfl_xor(s, 2, 64);
          s += __shfl_xor(s, 4, 64); s += __shfl_xor(s, 8, 64);
          if ((lane & 15) == 0) atomicAdd(&rs[g * 64 + rloc_g], s);
        }
    }
    __syncthreads();
    // coalesced store: 64 rows x 256 cols = 2048 uint4, 2 per thread
#pragma unroll
    for (int k2 = 0; k2 < 2; ++k2) {
      int idx = tid + k2 * 1024;
      int l = idx >> 5, u = idx & 31;
      int r = m0 + g * 64 + l;
      size_t obase = (size_t)((r & 31) * 32 + (r >> 5)) * 50200;
      *(uint4*)(outB + obase + n0 + u * 8) = *(const uint4*)(shp + l * 256 + u * 8);
    }
    __syncthreads();
  }
  if (tid < 256) atomicAdd(&rowsum[m0 + tid], rs[tid]);
}

// --------------------------- medium MFMA GEMM (BM=64, BN=128) --------------
template <int MODE>
__global__ __launch_bounds__(256) void gemm_med(const us* __restrict__ A,
                                                const us* __restrict__ BT,
                                                int M, int N, int K, int Ntiles,
                                                const float* __restrict__ bias,
                                                float bscale,
                                                us* __restrict__ outB) {
  __shared__ us As[64 * 32];
  __shared__ us Bs[128 * 32];
  const int tid = threadIdx.x, lane = tid & 63, w = tid >> 6;
  const int bx = blockIdx.x;
  const int mt = bx / Ntiles, nt = bx - mt * Ntiles;
  const int m0 = mt * 64, n0 = nt * 128;
  f32x4 acc[4][2] = {};
  for (int kk = 0; kk < K; kk += 32) {
    uint4 av, bv0, bv1;
    av = *(const uint4*)(A + (size_t)(m0 + (tid >> 2)) * K + kk + (tid & 3) * 8);
    {
      int i0 = tid * 2, i1 = tid * 2 + 1;
      bv0 = *(const uint4*)(BT + (size_t)(n0 + (i0 >> 2)) * K + kk + (i0 & 3) * 8);
      bv1 = *(const uint4*)(BT + (size_t)(n0 + (i1 >> 2)) * K + kk + (i1 & 3) * 8);
    }
    __syncthreads();
    ((uint4*)As)[tid] = av;
    ((uint4*)Bs)[tid * 2] = bv0;
    ((uint4*)Bs)[tid * 2 + 1] = bv1;
    __syncthreads();
    short8 af[4], bf0, bf1;
#pragma unroll
    for (int m = 0; m < 4; ++m)
      af[m] = *(const short8*)(As + (m * 16 + (lane & 15)) * 32 + (lane >> 4) * 8);
    bf0 = *(const short8*)(Bs + ((w * 2 + 0) * 16 + (lane & 15)) * 32 + (lane >> 4) * 8);
    bf1 = *(const short8*)(Bs + ((w * 2 + 1) * 16 + (lane & 15)) * 32 + (lane >> 4) * 8);
#pragma unroll
    for (int m = 0; m < 4; ++m) {
      acc[m][0] = __builtin_amdgcn_mfma_f32_16x16x32_bf16(af[m], bf0, acc[m][0], 0, 0, 0);
      acc[m][1] = __builtin_amdgcn_mfma_f32_16x16x32_bf16(af[m], bf1, acc[m][1], 0, 0, 0);
    }
  }
#pragma unroll
  for (int m = 0; m < 4; ++m)
#pragma unroll
    for (int q = 0; q < 2; ++q)
#pragma unroll
      for (int reg = 0; reg < 4; ++reg) {
        int r = m0 + m * 16 + (lane >> 4) * 4 + reg;
        int c = n0 + (w * 2 + q) * 16 + (lane & 15);
        float v = acc[m][q][reg];
        if (MODE == 0) v += bscale * bias[c];
        else v = ftanh_fast(v);
        outB[(size_t)r * N + c] = f2bf(v);
      }
}

// --------------------------- fat kernel (r7 classes) -----------------------
// 0-7 GRU | 8-207 pkc | 208-307 pku | 308-829 WT | 830-1107 encTp |
// 1108-1154 uveTp. 58KB pool, 2 blocks/CU.
struct FP {
  const us* frag; const us* gib; const float* bhh; const float* hidden0;
  us* hball; int* arrive;
  const us* encb; const us* WkcT; const float* bkc; us* pkc;
  const us* uve; const us* WkuT; const float* bku; us* pku;
  const float* Wgen; us* WT;
  const float* enc; us* encTp;
  us* uveTp;
};

__device__ void gru_body(const FP& P, int q, int tid, char* pool) {
  us* hs = (us*)pool;                  // 32 KB
  float* gh = (float*)(pool + 32768);  // 25344 B
  const int lane = tid & 63, w = tid >> 6;
  short8 bfr[16];
  {
    const us* fb = P.frag + (((size_t)(q * 12 + w) * 16) * 64 + lane) * 8;
#pragma unroll
    for (int kt = 0; kt < 16; ++kt) bfr[kt] = *(const short8*)(fb + (size_t)kt * 512);
  }
  float hprev[3], bh0[3], bh1[3], bh2[3];
#pragma unroll
  for (int s = 0; s < 3; ++s) {
    int i = tid + s * 768;
    if (i < 2048) {
      int b = i >> 6, jj = i & 63, j = q * 64 + jj;
      hprev[s] = P.hidden0[b * 512 + j];
      bh0[s] = P.bhh[j]; bh1[s] = P.bhh[512 + j]; bh2[s] = P.bhh[1024 + j];
    }
  }
  const int sw = (lane & 7) << 3;
  for (int t = 0; t < 32; ++t) {
    // prefetch this step's gi gates into regs (gib is launch-constant; loads
    // fly during the flag spin)
    float gi0[3], gi1[3], gi2[3];
#pragma unroll
    for (int s = 0; s < 3; ++s) {
      int i = tid + s * 768;
      if (i < 2048) {
        int b = i >> 6, jj = i & 63, j = q * 64 + jj;
        size_t gbase = (size_t)(t * 32 + b) * 1536;
        gi0[s] = bf2f(P.gib[gbase + j]);
        gi1[s] = bf2f(P.gib[gbase + 512 + j]);
        gi2[s] = bf2f(P.gib[gbase + 1024 + j]);
      }
    }
    if (t > 0) {
      if (tid == 0) {
        while (__hip_atomic_load(P.arrive + (t - 1), __ATOMIC_ACQUIRE,
                                 __HIP_MEMORY_SCOPE_AGENT) < 8) {
          __builtin_amdgcn_s_sleep(1);
        }
      }
      __syncthreads();
    }
    const us* hp = P.hball + (size_t)t * 16384;
    for (int i = tid; i < 2048; i += 768)
      ((uint4*)hs)[i ^ ((i >> 6) & 7)] = *(const uint4*)(hp + i * 8);
    __syncthreads();
    f32x4 acc0 = {}, acc1 = {};
#pragma unroll
    for (int kt = 0; kt < 16; ++kt) {
      int base0 = ((lane & 15) * 512 + kt * 32 + (lane >> 4) * 8) ^ sw;
      int base1 = (((lane & 15) + 16) * 512 + kt * 32 + (lane >> 4) * 8) ^ sw;
      short8 a0 = *(const short8*)(hs + base0);
      short8 a1 = *(const short8*)(hs + base1);
      acc0 = __builtin_amdgcn_mfma_f32_16x16x32_bf16(a0, bfr[kt], acc0, 0, 0, 0);
      acc1 = __builtin_amdgcn_mfma_f32_16x16x32_bf16(a1, bfr[kt], acc1, 0, 0, 0);
    }
    {
      int col = w * 16 + (lane & 15);
#pragma unroll
      for (int reg = 0; reg < 4; ++reg) {
        gh[col * 33 + ((lane >> 4) * 4 + reg)] = acc0[reg];
        gh[col * 33 + (16 + (lane >> 4) * 4 + reg)] = acc1[reg];
      }
    }
    __syncthreads();
    us* hbn = P.hball + (size_t)(t + 1) * 16384;
#pragma unroll
    for (int s = 0; s < 3; ++s) {
      int i = tid + s * 768;
      if (i < 2048) {
        int b = i >> 6, jj = i & 63, j = q * 64 + jj;
        float g0 = gh[jj * 33 + b] + bh0[s];
        float g1 = gh[(64 + jj) * 33 + b] + bh1[s];
        float g2 = gh[(128 + jj) * 33 + b] + bh2[s];
        float r_ = fsigmoid(gi0[s] + g0);
        float z_ = fsigmoid(gi1[s] + g1);
        float n_ = ftanh(gi2[s] + r_ * g2);
        float hv = (1.f - z_) * n_ + z_ * hprev[s];
        hprev[s] = hv;
        hbn[b * 512 + j] = f2bf(hv);
      }
    }
    __syncthreads();  // drains h stores
    if (tid == 0)
      __hip_atomic_fetch_add(P.arrive + t, 1, __ATOMIC_RELEASE,
                             __HIP_MEMORY_SCOPE_AGENT);
  }
}

// BM=256 BN=128 tile; active tid<512, all threads hit barriers.
__device__ void gemm0_body(const us* A, const us* BT, int N, int K,
                           int mt, int nt, const float* bias, float bscale,
                           us* outB, int tid, char* pool) {
  us* As = (us*)pool;
  us* Bs = (us*)(pool + 16384);
  const bool act = tid < 512;
  const int lane = tid & 63, wid = (tid >> 6) & 7;
  const int wr = wid >> 1, wc = wid & 1;
  const int m0 = mt * 256, n0 = nt * 128;
  f32x4 acc[4][4] = {};
  for (int kk = 0; kk < K; kk += 32) {
    uint4 av0 = {0, 0, 0, 0}, av1 = {0, 0, 0, 0}, bv = {0, 0, 0, 0};
    if (act) {
      int c = tid, row = c >> 2, c8 = (c & 3) * 8;
      av0 = *(const uint4*)(A + (size_t)(m0 + row) * K + kk + c8);
      av1 = *(const uint4*)(A + (size_t)(m0 + 128 + row) * K + kk + c8);
      int nr = n0 + row; if (nr > N - 1) nr = N - 1;
      bv = *(const uint4*)(BT + (size_t)nr * K + kk + c8);
    }
    __syncthreads();
    if (act) {
      ((uint4*)As)[tid] = av0;
      ((uint4*)As)[tid + 512] = av1;
      ((uint4*)Bs)[tid] = bv;
    }
    __syncthreads();
    if (act) {
      short8 af[4], bfr[4];
#pragma unroll
      for (int m = 0; m < 4; ++m)
        af[m] = *(const short8*)(As + (wr * 64 + m * 16 + (lane & 15)) * 32 + (lane >> 4) * 8);
#pragma unroll
      for (int n = 0; n < 4; ++n)
        bfr[n] = *(const short8*)(Bs + (wc * 64 + n * 16 + (lane & 15)) * 32 + (lane >> 4) * 8);
#pragma unroll
      for (int m = 0; m < 4; ++m)
#pragma unroll
        for (int n = 0; n < 4; ++n)
          acc[m][n] = __builtin_amdgcn_mfma_f32_16x16x32_bf16(af[m], bfr[n], acc[m][n], 0, 0, 0);
    }
  }
  if (act) {
#pragma unroll
    for (int m = 0; m < 4; ++m)
#pragma unroll
      for (int n = 0; n < 4; ++n)
#pragma unroll
        for (int reg = 0; reg < 4; ++reg) {
          int r = m0 + wr * 64 + m * 16 + (lane >> 4) * 4 + reg;
          int c = n0 + wc * 64 + n * 16 + (lane & 15);
          outB[(size_t)r * N + c] = f2bf(acc[m][n][reg] + bscale * bias[c]);
        }
  }
}

__global__ __launch_bounds__(768, 1) void k_fat(FP P) {
  __shared__ char pool[58368];
  const int bid = blockIdx.x, tid = threadIdx.x;
  if (bid < 8) { gru_body(P, bid, tid, pool); return; }
  if (bid < 208) {  // pkc: 50 mt x 4 nt
    int j = bid - 8;
    gemm0_body(P.encb, P.WkcT, 512, 1024, j >> 2, j & 3, P.bkc, SCW, P.pkc, tid, pool);
    return;
  }
  if (bid < 308) {  // pku: 25 mt x 4 nt
    int j = bid - 208;
    gemm0_body(P.uve, P.WkuT, 512, 320, j >> 2, j & 3, P.bku, SCW, P.pku, tid, pool);
    return;
  }
  // transpose classes: 3 x 256-thread groups, 16 iterations
  const int g = tid >> 8, lt = tid & 255;
  const int tx = lt & 31, ty = lt >> 5;
  float* tb = (float*)(pool + g * 4224);
  if (bid < 830) {  // WT: 25008 subjobs, stride 1566
    int base = (bid - 308) * 3 + g;
    for (int it = 0; it < 16; ++it) {
      int sub = base + it * 1566;
      bool valid = sub < 25008;
      int x = valid ? sub % 1563 : 0, y = valid ? sub / 1563 : 0;
      int c0 = x * 32, r0 = y * 32;
      if (valid) {
#pragma unroll
        for (int i = 0; i < 4; ++i) {
          int r = r0 + ty + i * 8, c = c0 + tx;
          tb[(ty + i * 8) * 33 + tx] =
              (c < 50000) ? P.Wgen[(size_t)r * 50000 + c] : 0.f;
        }
      }
      __syncthreads();
      if (valid) {
#pragma unroll
        for (int i = 0; i < 4; ++i) {
          int c = c0 + ty + i * 8;
          if (c < 50000)
            P.WT[(size_t)c * 512 + r0 + tx] = f2bf(tb[tx * 33 + ty + i * 8]);
        }
      }
      __syncthreads();
    }
    return;
  }
  if (bid < 1108) {  // encTp: 13312 subjobs, stride 834
    int base = (bid - 830) * 3 + g;
    for (int it = 0; it < 16; ++it) {
      int sub = base + it * 834;
      bool valid = sub < 13312;
      int x = sub & 31, rem = sub >> 5;
      int y = rem % 13, z = rem / 13;
      const float* src = P.enc + (size_t)z * 409600;
      us* dst = P.encTp + (size_t)z * 425984;
      int c0 = x * 32, r0 = y * 32;
      if (valid) {
#pragma unroll
        for (int i = 0; i < 4; ++i) {
          int r = r0 + ty + i * 8, c = c0 + tx;
          tb[(ty + i * 8) * 33 + tx] = (r < 400) ? src[(size_t)r * 1024 + c] : 0.f;
        }
      }
      __syncthreads();
      if (valid) {
#pragma unroll
        for (int i = 0; i < 4; ++i) {
          int c = c0 + ty + i * 8, rr = r0 + tx;
          if (rr < 416) dst[(size_t)c * 416 + rr] = f2bf(tb[tx * 33 + ty + i * 8]);
        }
      }
      __syncthreads();
    }
    return;
  }
  {  // uveTp: 2240 subjobs, stride 141
    us* tbu = (us*)tb;
    int base = (bid - 1108) * 3 + g;
    for (int it = 0; it < 16; ++it) {
      int sub = base + it * 141;
      bool valid = sub < 2240;
      int x = sub % 10, rem = sub / 10;
      int y = rem % 7, z = rem / 7;
      const us* src = P.uve + (size_t)z * 64000;
      us* dst = P.uveTp + (size_t)z * 71680;
      int c0 = x * 32, r0 = y * 32;
      if (valid) {
#pragma unroll
        for (int i = 0; i < 4; ++i) {
          int r = r0 + ty + i * 8, c = c0 + tx;
          tbu[(ty + i * 8) * 33 + tx] = (r < 200) ? src[(size_t)r * 320 + c] : (us)0;
        }
      }
      __syncthreads();
      if (valid) {
#pragma unroll
        for (int i = 0; i < 4; ++i) {
          int c = c0 + ty + i * 8, rr = r0 + tx;
          if (rr < 224) dst[(size_t)c * 224 + rr] = tbu[tx * 33 + ty + i * 8];
        }
      }
      __syncthreads();
    }
  }
}

// --------------------------- batched scores --------------------------------
// 2432 blocks: enc 1600 (32 b x 25 s-chunks x 2 t-halves), usr 832 (32x13x2).
__global__ __launch_bounds__(256) void k_scores(const us* __restrict__ Qall,
                                                const us* __restrict__ pkc,
                                                const us* __restrict__ pku,
                                                const float* __restrict__ wec,
                                                const float* __restrict__ bec,
                                                const float* __restrict__ weu,
                                                const float* __restrict__ beu,
                                                const int* __restrict__ src_mask,
                                                float* __restrict__ sc_enc,
                                                float* __restrict__ sc_usr) {
  __shared__ us q[16 * 512];
  const int bid = blockIdx.x;
  const bool enc = bid < 1600;
  int b, s0, th, qoff, S;
  if (enc) {
    b = bid / 50;
    int r = bid % 50;
    s0 = (r >> 1) * 16; th = r & 1; qoff = 0; S = 400;
  } else {
    int j = bid - 1600;
    b = j / 26;
    int r = j % 26;
    s0 = (r >> 1) * 16; th = r & 1; qoff = 512; S = 200;
  }
  for (int i = threadIdx.x; i < 1024; i += 256) {
    int tt = th * 16 + (i >> 6), c8 = (i & 63) * 8;
    ((uint4*)q)[i] = *(const uint4*)(Qall + (size_t)(tt * 32 + b) * 1024 + qoff + c8);
  }
  const int w = threadIdx.x >> 6, lane = threadIdx.x & 63;
  const int d0 = lane * 8;
  const float* we = enc ? wec : weu;
  float wef[8];
  {
    float4 w0 = *(const float4*)(we + d0);
    float4 w1 = *(const float4*)(we + d0 + 4);
    wef[0] = w0.x; wef[1] = w0.y; wef[2] = w0.z; wef[3] = w0.w;
    wef[4] = w1.x; wef[5] = w1.y; wef[6] = w1.z; wef[7] = w1.w;
  }
  const float bias = enc ? bec[0] : beu[0];
  float pkf[4][8];
  int ss[4], validv[4], maskedv[4];
#pragma unroll
  for (int si = 0; si < 4; ++si) {
    int s = s0 + w * 4 + si;
    validv[si] = (s < S);
    int sc = validv[si] ? s : (S - 1);
    ss[si] = sc;
    const us* pk = enc ? pkc + ((size_t)b * 400 + sc) * 512
                       : pku + ((size_t)b * 200 + sc) * 512;
    unpack8(*(const uint4*)(pk + d0), pkf[si]);
    maskedv[si] = enc ? (src_mask[b * 400 + sc] == 0) : 0;
  }
  __syncthreads();
  for (int tl = 0; tl < 16; ++tl) {
    short8 qv = *(const short8*)(q + tl * 512 + d0);
    float qf[8];
#pragma unroll
    for (int d = 0; d < 8; ++d) qf[d] = bf2f((us)qv[d]);
#pragma unroll
    for (int si = 0; si < 4; ++si) {
      float a = 0.f;
#pragma unroll
      for (int d = 0; d < 8; ++d) {
        float x = qf[d] + pkf[si][d];  // = SCW*(q+pk), SCW < 0
        float u = exp2f(-fabsf(x));
        float r2v = (1.f - u) * __builtin_amdgcn_rcpf(1.f + u);
        a = fmaf(copysignf(r2v, -x), wef[d], a);
      }
#pragma unroll
      for (int m = 1; m < 64; m <<= 1) a += __shfl_xor(a, m, 64);
      if (lane == 0 && validv[si]) {
        int t = th * 16 + tl;
        float v = a + bias;
        if (enc) sc_enc[(size_t)(t * 32 + b) * 400 + ss[si]] = maskedv[si] ? -1e9f : v;
        else sc_usr[(size_t)(t * 32 + b) * 200 + ss[si]] = v;
      }
    }
  }
}

// --------------------------- softmax + cat + gate-h ------------------------
__device__ __forceinline__ float bmax256(float v, float* r4, int tid) {
#pragma unroll
  for (int m = 1; m < 64; m <<= 1) v = fmaxf(v, __shfl_xor(v, m, 64));
  if ((tid & 63) == 0) r4[tid >> 6] = v;
  __syncthreads();
  float x = fmaxf(fmaxf(r4[0], r4[1]), fmaxf(r4[2], r4[3]));
  __syncthreads();
  return x;
}
__device__ __forceinline__ float bsum256(float v, float* r4, int tid) {
#pragma unroll
  for (int m = 1; m < 64; m <<= 1) v += __shfl_xor(v, m, 64);
  if ((tid & 63) == 0) r4[tid >> 6] = v;
  __syncthreads();
  float x = r4[0] + r4[1] + r4[2] + r4[3];
  __syncthreads();
  return x;
}

// grid 2432: [0,1024) enc softmax | [1024,2048) usr softmax |
// [2048,2304) cat h/ue (4 rows/blk) | [2304,2432) gate-h (8 rows/blk)
__global__ __launch_bounds__(256) void k_soft2(const float* __restrict__ sc_enc,
                                               const float* __restrict__ sc_usr,
                                               us* __restrict__ AC,
                                               us* __restrict__ AU,
                                               float* __restrict__ aual,
                                               float* __restrict__ cp_acc,
                                               const us* __restrict__ hball,
                                               const float* __restrict__ ue,
                                               const float* __restrict__ Wg,
                                               us* __restrict__ catall) {
  __shared__ float r4[4];
  int bid = blockIdx.x, tid = threadIdx.x;
  if (bid < 1024) {
    int t = bid >> 5, b = bid & 31;
    float v0 = (tid < 400) ? sc_enc[(size_t)bid * 400 + tid] : -3e38f;
    float v1 = (tid + 256 < 400) ? sc_enc[(size_t)bid * 400 + tid + 256] : -3e38f;
    float mx = bmax256(fmaxf(v0, v1), r4, tid);
    float e0 = (tid < 400) ? __expf(v0 - mx) : 0.f;
    float e1 = (tid + 256 < 400) ? __expf(v1 - mx) : 0.f;
    float inv = 1.f / bsum256(e0 + e1, r4, tid);
    us* ACb = AC + (size_t)(b * 32 + t) * 416;
    if (tid < 400) ACb[tid] = f2bf(e0 * inv);
    int s2 = tid + 256;
    if (s2 < 400) ACb[s2] = f2bf(e1 * inv);
    else if (s2 < 416) ACb[s2] = 0;
  } else if (bid < 2048) {
    int rr = bid - 1024;
    int t = rr >> 5, b = rr & 31;
    float v0 = (tid < 200) ? sc_usr[(size_t)rr * 200 + tid] : -3e38f;
    float mx = bmax256(v0, r4, tid);
    float e0 = (tid < 200) ? __expf(v0 - mx) : 0.f;
    float inv = 1.f / bsum256(e0, r4, tid);
    us* AUb = AU + (size_t)(b * 32 + t) * 224;
    if (tid < 200) {
      float a = e0 * inv;
      AUb[tid] = f2bf(a);
      aual[(size_t)rr * 200 + tid] = a;
    } else if (tid < 224) {
      AUb[tid] = 0;
    }
  } else if (bid < 2304) {
    int w = tid >> 6, lane = tid & 63;
    int row = (bid - 2048) * 4 + w;
    int t = row >> 5, b = row & 31;
    us* rowp = catall + (size_t)row * 2144;
    const us* hb = hball + (size_t)(t + 1) * 16384 + b * 512;
    *(uint4*)(rowp + lane * 8) = *(const uint4*)(hb + lane * 8);
    for (int i = lane; i < 308; i += 64)
      rowp[1836 + i] = (i < 300) ? f2bf(ue[b * 300 + i]) : (us)0;
  } else {
    int w = tid >> 6, lane = tid & 63, d0 = lane * 8;
#pragma unroll
    for (int k = 0; k < 2; ++k) {
      int row = (bid - 2304) * 8 + w * 2 + k;
      int t = row >> 5, b = row & 31;
      float hv[8];
      unpack8(*(const uint4*)(hball + (size_t)(t + 1) * 16384 + b * 512 + d0), hv);
      float4 g0 = *(const float4*)(Wg + 1024 + d0);
      float4 g1 = *(const float4*)(Wg + 1024 + d0 + 4);
      float a = hv[0] * g0.x + hv[1] * g0.y + hv[2] * g0.z + hv[3] * g0.w +
                hv[4] * g1.x + hv[5] * g1.y + hv[6] * g1.z + hv[7] * g1.w;
#pragma unroll
      for (int m = 1; m < 64; m <<= 1) a += __shfl_xor(a, m, 64);
      if (lane == 0) atomicAdd(&cp_acc[row], a);
    }
  }
}

// --------------------------- merged ctx GEMM -------------------------------
__device__ void ctx_core(const us* Ab, const us* Bb, const float* Wg,
                         us* catall, float* cp_acc, int b, int N, int Kp,
                         int n0, int catOff, int wgOff, int Nvalid, int tid,
                         us* As, us* Bs, float* gaccs) {
  const int lane = tid & 63, w = tid >> 6;
  if (tid < 32) gaccs[tid] = 0.f;
  f32x4 acc[2][2] = {};
  for (int kk = 0; kk < Kp; kk += 32) {
    uint4 av, bv0, bv1;
    if (tid < 128) av = *(const uint4*)(Ab + (size_t)(tid >> 2) * Kp + kk + (tid & 3) * 8);
    {
      int i0 = tid * 2, row0 = i0 >> 2, c0 = (i0 & 3) * 8;
      int i1 = tid * 2 + 1, row1 = i1 >> 2, c1 = (i1 & 3) * 8;
      int nr0 = n0 + row0; if (nr0 > N - 1) nr0 = N - 1;
      int nr1 = n0 + row1; if (nr1 > N - 1) nr1 = N - 1;
      bv0 = *(const uint4*)(Bb + (size_t)nr0 * Kp + kk + c0);
      bv1 = *(const uint4*)(Bb + (size_t)nr1 * Kp + kk + c1);
    }
    __syncthreads();
    if (tid < 128) ((uint4*)As)[tid] = av;
    ((uint4*)Bs)[tid * 2] = bv0;
    ((uint4*)Bs)[tid * 2 + 1] = bv1;
    __syncthreads();
    short8 a0 = *(const short8*)(As + ((lane & 15)) * 32 + (lane >> 4) * 8);
    short8 a1 = *(const short8*)(As + (16 + (lane & 15)) * 32 + (lane >> 4) * 8);
#pragma unroll
    for (int qq = 0; qq < 2; ++qq) {
      short8 bf_ = *(const short8*)(Bs + ((w * 2 + qq) * 16 + (lane & 15)) * 32 + (lane >> 4) * 8);
      acc[0][qq] = __builtin_amdgcn_mfma_f32_16x16x32_bf16(a0, bf_, acc[0][qq], 0, 0, 0);
      acc[1][qq] = __builtin_amdgcn_mfma_f32_16x16x32_bf16(a1, bf_, acc[1][qq], 0, 0, 0);
    }
  }
#pragma unroll
  for (int mt = 0; mt < 2; ++mt)
#pragma unroll
    for (int qq = 0; qq < 2; ++qq)
#pragma unroll
      for (int reg = 0; reg < 4; ++reg) {
        int t_ = mt * 16 + (lane >> 4) * 4 + reg;
        int c = n0 + (w * 2 + qq) * 16 + (lane & 15);
        if (c < Nvalid) {
          float v = acc[mt][qq][reg];
          catall[(size_t)(t_ * 32 + b) * 2144 + catOff + c] = f2bf(v);
          atomicAdd(&gaccs[t_], v * Wg[wgOff + c]);
        }
      }
  __syncthreads();
  if (tid < 32) atomicAdd(&cp_acc[tid * 32 + b], gaccs[tid]);
}

// grid 352: [0,256) enc ctx | [256,352) usr ctx
__global__ __launch_bounds__(256) void k_ctx2(const us* __restrict__ AC,
                                              const us* __restrict__ encTp,
                                              const us* __restrict__ AU,
                                              const us* __restrict__ uveTp,
                                              const float* __restrict__ Wg,
                                              us* __restrict__ catall,
                                              float* __restrict__ cp_acc) {
  __shared__ us As[32 * 32];
  __shared__ us Bs[128 * 32];
  __shared__ float gaccs[32];
  int bid = blockIdx.x, tid = threadIdx.x;
  if (bid < 256) {
    int b = bid >> 3, nt = bid & 7;
    ctx_core(AC + (size_t)b * 32 * 416, encTp + (size_t)b * 1024 * 416, Wg,
             catall, cp_acc, b, 1024, 416, nt * 128, 512, 0, 1024, tid, As, Bs, gaccs);
  } else {
    int j = bid - 256;
    int b = j / 3, nt = j % 3;
    ctx_core(AU + (size_t)b * 32 * 224, uveTp + (size_t)b * 320 * 224, Wg,
             catall, cp_acc, b, 320, 224, nt * 128, 1536, 1536, 300, tid, As, Bs, gaccs);
  }
}

// --------------------------- finalize --------------------------------------
__global__ __launch_bounds__(256) void k_finalize(float* __restrict__ out,
                                                  const float* __restrict__ rowsum,
                                                  const float* __restrict__ cp_acc,
                                                  const float* __restrict__ bg,
                                                  const float* __restrict__ au_all,
                                                  const int* __restrict__ sv) {
  int r = blockIdx.x, t = threadIdx.x;
  int b = r & 31, tt = r >> 5;
  float cp = fsigmoid(cp_acc[r] + bg[0]);
  float scale = (1.f - cp) / rowsum[r];
  float* base = out + (size_t)(b * 32 + tt) * 50200;
  float4* b4 = (float4*)base;
  for (int i = t; i < 12550; i += 256) {
    if (i < 12500) {
      float4 v = b4[i];
      v.x *= scale; v.y *= scale; v.z *= scale; v.w *= scale;
      b4[i] = v;
    } else {
      b4[i] = make_float4(0.f, 0.f, 0.f, 0.f);
    }
  }
  __syncthreads();
  if (t < 200) {
    int idx = sv[b * 200 + t];
    atomicAdd(base + idx, cp * au_all[(size_t)r * 200 + t]);
  }
}

__global__ __launch_bounds__(256) void k_finalize2(const us* __restrict__ expb,
                                                   const float* __restrict__ rowsum,
                                                   const float* __restrict__ cp_acc,
                                                   const float* __restrict__ bg,
                                                   const float* __restrict__ au_all,
                                                   const int* __restrict__ sv,
                                                   float* __restrict__ out) {
  int r = blockIdx.x, t = threadIdx.x;
  int b = r & 31, tt = r >> 5;
  float cp = fsigmoid(cp_acc[r] + bg[0]);
  float scale = (1.f - cp) / rowsum[r];
  size_t obase = (size_t)(b * 32 + tt) * 50200;
  const uint4* eb = (const uint4*)(expb + obase);
  float4* ob = (float4*)(out + obase);
  for (int i = t; i < 6275; i += 256) {
    float4 o0, o1;
    if (i < 6250) {
      uint4 ev = eb[i];
      o0.x = bf2f((us)(ev.x & 0xffff)) * scale; o0.y = bf2f((us)(ev.x >> 16)) * scale;
      o0.z = bf2f((us)(ev.y & 0xffff)) * scale; o0.w = bf2f((us)(ev.y >> 16)) * scale;
      o1.x = bf2f((us)(ev.z & 0xffff)) * scale; o1.y = bf2f((us)(ev.z >> 16)) * scale;
      o1.z = bf2f((us)(ev.w & 0xffff)) * scale; o1.w = bf2f((us)(ev.w >> 16)) * scale;
    } else {
      o0 = make_float4(0.f, 0.f, 0.f, 0.f);
      o1 = o0;
    }
    ob[i * 2] = o0;
    ob[i * 2 + 1] = o1;
  }
  __syncthreads();
  if (t < 200) {
    int idx = sv[b * 200 + t];
    atomicAdd(out + obase + idx, cp * au_all[(size_t)r * 200 + t]);
  }
}

// ---------------------------------------------------------------------------

extern "C" void kernel_launch(void* const* d_in, const int* in_sizes, int n_in,
                              void* d_out, int out_size, void* d_ws, size_t ws_size,
                              hipStream_t stream) {
  (void)in_sizes; (void)n_in; (void)out_size;
  const float* enc = (const float*)d_in[0];
  const float* hidden0 = (const float*)d_in[1];
  const float* user_embed = (const float*)d_in[2];
  const float* W_embed = (const float*)d_in[3];
  const float* W_ih = (const float*)d_in[4];
  const float* W_hh = (const float*)d_in[5];
  const float* b_ih = (const float*)d_in[6];
  const float* b_hh = (const float*)d_in[7];
  const float* Wk_c = (const float*)d_in[8];
  const float* bk_c = (const float*)d_in[9];
  const float* Wq_c = (const float*)d_in[10];
  const float* bq_c = (const float*)d_in[11];
  const float* we_c = (const float*)d_in[12];
  const float* be_c = (const float*)d_in[13];
  const float* Wk_u = (const float*)d_in[14];
  const float* bk_u = (const float*)d_in[15];
  const float* Wq_u = (const float*)d_in[16];
  const float* bq_u = (const float*)d_in[17];
  const float* we_u = (const float*)d_in[18];
  const float* be_u = (const float*)d_in[19];
  const float* Wc = (const float*)d_in[20];
  const float* Wg = (const float*)d_in[21];
  const float* bg = (const float*)d_in[22];
  const float* Wgen = (const float*)d_in[23];
  const int* src_mask = (const int*)d_in[24];
  const int* tgt = (const int*)d_in[25];
  const int* sv = (const int*)d_in[26];
  float* out = (float*)d_out;

  // ---------------- workspace layout ----------------
  char* base = (char*)d_ws;
  size_t off = 0;
  auto take = [&](size_t bytes) {
    char* p = base + off;
    off += (bytes + 255) & ~(size_t)255;
    return p;
  };
  us* WT = (us*)take(50000ull * 512 * 2);
  char* R0 = take(32ull * 1024 * 416 * 2);  // encb (encTp fallback)
  us* encb = (us*)R0;
  char* RCD = take(12800ull * 512 * 2 + 6400ull * 512 * 2);
  us* pkc = (us*)RCD;
  us* pku = (us*)(RCD + 12800ull * 512 * 2);
  us* AC = (us*)RCD;
  us* AU = (us*)(RCD + 860160);
  float* aual = (float*)(RCD + 860160 + 458752);
  us* catall = (us*)(RCD + 860160 + 458752 + 819200);
  us* chb = (us*)(RCD + 860160 + 458752 + 819200 + 4390912);
  us* uve = (us*)take(6400ull * 320 * 2);
  us* uveTp = (us*)take(32ull * 320 * 224 * 2);
  char* RG = take(2700000);  // WkcT | WihT | xe
  us* WkcT = (us*)RG;
  us* WihT = (us*)(RG + 1048576);
  us* xe = (us*)(RG + 1048576 + 983040);
  us* WkuT = (us*)take(512ull * 320 * 2);
  us* WqcuT = (us*)take(1024ull * 512 * 2);
  us* WcT = (us*)take(512ull * 2144 * 2);
  us* WhhF = (us*)take(1536ull * 512 * 2);
  us* gib = (us*)take(1024ull * 1536 * 2);
  us* hball = (us*)take(33ull * 16384 * 2);
  us* Qall = (us*)take(1024ull * 1024 * 2);
  float* sc_enc = (float*)take(1024ull * 400 * 4);
  float* sc_usr = (float*)take(1024ull * 200 * 4);
  float* bqcu = (float*)take(1024 * 4);
  float* cp_acc = (float*)take(1024 * 4);
  float* rsum = (float*)take(1024 * 4);
  int* arrive = (int*)take(32 * 4);
  size_t expb_bytes = 1024ull * 50200 * 2;
  bool big_ws = (ws_size >= off + expb_bytes + 256);
  us* expb = big_ws ? (us*)take(expb_bytes) : nullptr;
  us* encTp = big_ws ? expb : (us*)R0;

  hipMemcpyAsync(bqcu, bq_c, 512 * 4, hipMemcpyDeviceToDevice, stream);
  hipMemcpyAsync(bqcu + 512, bq_u, 512 * 4, hipMemcpyDeviceToDevice, stream);
  hipMemsetAsync(rsum, 0, 1024 * 4, stream);
  hipMemsetAsync(cp_acc, 0, 1024 * 4, stream);
  hipMemsetAsync(arrive, 0, 32 * 4, stream);

  // ---------------- merged precompute + gib ----------------
  PP pp;
  pp.enc = enc; pp.hidden0 = hidden0; pp.Wk_c = Wk_c; pp.Wk_u = Wk_u;
  pp.Wq_c = Wq_c; pp.Wq_u = Wq_u; pp.Wc = Wc; pp.W_ih = W_ih; pp.W_hh = W_hh;
  pp.W_embed = W_embed; pp.tgt = tgt; pp.sv = sv;
  pp.encb = encb; pp.hball = hball; pp.WkcT = WkcT; pp.WkuT = WkuT;
  pp.WqcuT = WqcuT; pp.WcT = WcT; pp.WihT = WihT; pp.WhhF = WhhF;
  pp.xe = xe; pp.uve = uve;
  k_prep<<<5920, 256, 0, stream>>>(pp);
  gemm_med<0><<<192, 256, 0, stream>>>(xe, WihT, 1024, 1536, 320, 12, b_ih, 1.f, gib);

  FP fp;
  fp.frag = WhhF; fp.gib = gib; fp.bhh = b_hh; fp.hidden0 = hidden0;
  fp.hball = hball; fp.arrive = arrive;
  fp.encb = encb; fp.WkcT = WkcT; fp.bkc = bk_c; fp.pkc = pkc;
  fp.uve = uve; fp.WkuT = WkuT; fp.bku = bk_u; fp.pku = pku;
  fp.Wgen = Wgen; fp.WT = WT; fp.enc = enc; fp.encTp = encTp; fp.uveTp = uveTp;

  if (big_ws) {
    // fat: GRU + pkc/pku GEMMs + WT/encTp/uveTp transposes overlapped
    k_fat<<<1155, 768, 0, stream>>>(fp);
  } else {
    // serial fallback
    k_tcastX<<<dim3(1563, 16, 1), 256, 0, stream>>>(Wgen, WT, 512, 50000, 512, 0, 0);
    gemm_bt<0><<<200, 512, 0, stream>>>(encb, WkcT, 12800, 512, 1024, 4, bk_c, SCW,
                                        pkc, nullptr, nullptr);
    gemm_bt<0><<<100, 512, 0, stream>>>(uve, WkuT, 6400, 512, 320, 4, bk_u, SCW,
                                        pku, nullptr, nullptr);
    k_tcastX<<<dim3(32, 13, 32), 256, 0, stream>>>(enc, encTp, 400, 1024, 416,
                                                   400ull * 1024, 1024ull * 416);
    k_tcastXb<<<dim3(10, 7, 32), 256, 0, stream>>>(uve, uveTp, 200, 320, 224,
                                                   200ull * 320, 320ull * 224);
    k_fat<<<8, 768, 0, stream>>>(fp);  // GRU only
  }

  // ---------------- batched attention + output ----------------
  gemm_med<0><<<128, 256, 0, stream>>>(hball + 16384, WqcuT, 1024, 1024, 512, 8,
                                       bqcu, SCW, Qall);
  k_scores<<<2432, 256, 0, stream>>>(Qall, pkc, pku, we_c, be_c, we_u, be_u,
                                     src_mask, sc_enc, sc_usr);
  k_soft2<<<2432, 256, 0, stream>>>(sc_enc, sc_usr, AC, AU, aual, cp_acc,
                                    hball, user_embed, Wg, catall);
  k_ctx2<<<352, 256, 0, stream>>>(AC, encTp, AU, uveTp, Wg, catall, cp_acc);
  gemm_med<2><<<64, 256, 0, stream>>>(catall, WcT, 1024, 512, 2144, 4, nullptr,
                                      1.f, chb);
  if (big_ws) {
    gemm_v<<<784, 1024, 0, stream>>>(chb, WT, expb, rsum);
    k_finalize2<<<1024, 256, 0, stream>>>(expb, rsum, cp_acc, bg, aual, sv, out);
  } else {
    gemm_bt<1, true><<<4 * 391, 512, 0, stream>>>(chb, WT, 1024, 50000, 512, 391,
                                                  nullptr, 1.f, nullptr, out, rsum);
    k_finalize<<<1024, 256, 0, stream>>>(out, rsum, cp_acc, bg, aual, sv);
  }
}

// Round 14
// 664.943 us; speedup vs baseline: 1.0607x; 1.0607x over previous
//
#include <hip/hip_runtime.h>

// ---------------------------------------------------------------------------
// Pointer-generator decoder. B=32 S=400 H=512 E=300 Vs=200 T=32 EN=50000 V=50200
// Round 14: consolidation of best-measured pieces = r11 kernel set (vocab via
// gemm_bt<3,true> with LDS-bounce stores; gemm_v reverted) + r13's GRU gi/bhh
// register prefetch (k_fat 212->195 measured).
// ---------------------------------------------------------------------------

typedef __attribute__((ext_vector_type(8))) short short8;
typedef __attribute__((ext_vector_type(4))) float f32x4;
typedef unsigned short us;

#define SCW (-2.8853900817779268f)  // -2*log2(e)

__device__ __forceinline__ float bf2f(us u) {
  return __uint_as_float(((unsigned)u) << 16);
}
__device__ __forceinline__ us f2bf(float f) {
  unsigned x = __float_as_uint(f);
  unsigned r = x + 0x7fffu + ((x >> 16) & 1u);
  return (us)(r >> 16);
}
__device__ __forceinline__ float fsigmoid(float x) { return 1.f / (1.f + __expf(-x)); }
__device__ __forceinline__ float ftanh(float x) {
  float t = __expf(-2.f * fabsf(x));
  float r = (1.f - t) / (1.f + t);
  return x >= 0.f ? r : -r;
}
__device__ __forceinline__ float ftanh_fast(float x) {
  float u = exp2f(SCW * fabsf(x));
  float r = (1.f - u) * __builtin_amdgcn_rcpf(1.f + u);
  return copysignf(r, x);
}
__device__ __forceinline__ void unpack8(uint4 v, float* f) {
  f[0] = bf2f((us)(v.x & 0xffff)); f[1] = bf2f((us)(v.x >> 16));
  f[2] = bf2f((us)(v.y & 0xffff)); f[3] = bf2f((us)(v.y >> 16));
  f[4] = bf2f((us)(v.z & 0xffff)); f[5] = bf2f((us)(v.z >> 16));
  f[6] = bf2f((us)(v.w & 0xffff)); f[7] = bf2f((us)(v.w >> 16));
}

// --------------------------- merged precompute kernel ----------------------
struct PP {
  const float *enc, *hidden0, *Wk_c, *Wk_u, *Wq_c, *Wq_u, *Wc, *W_ih, *W_hh, *W_embed;
  const int *tgt, *sv;
  us *encb, *hball, *WkcT, *WkuT, *WqcuT, *WcT, *WihT, *WhhF, *xe, *uve;
};

__device__ void tcast_job(const float* __restrict__ src, us* __restrict__ dst,
                          int R, int C, int Rpad, int x, int y, float scale,
                          int lt, float* tb) {
  int tx = lt & 31, ty = lt >> 5;
  int c0 = x * 32, r0 = y * 32;
#pragma unroll
  for (int i = 0; i < 4; ++i) {
    int r = r0 + ty + i * 8, c = c0 + tx;
    tb[(ty + i * 8) * 33 + tx] = (r < R && c < C) ? src[(size_t)r * C + c] : 0.f;
  }
  __syncthreads();
#pragma unroll
  for (int i = 0; i < 4; ++i) {
    int c = c0 + ty + i * 8, rr = r0 + tx;
    if (c < C && rr < Rpad)
      dst[(size_t)c * Rpad + rr] = f2bf(scale * tb[tx * 33 + ty + i * 8]);
  }
}

__global__ __launch_bounds__(256) void k_prep(PP P) {
  __shared__ float tb[32 * 33];
  const int bid = blockIdx.x, tid = threadIdx.x;
  if (bid < 1024) {
    for (int i = bid * 256 + tid; i < 3276800; i += 1024 * 256) {
      float4 v = ((const float4*)P.enc)[i];
      ushort4 o;
      o.x = f2bf(v.x); o.y = f2bf(v.y); o.z = f2bf(v.z); o.w = f2bf(v.w);
      ((ushort4*)P.encb)[i] = o;
    }
  } else if (bid < 1040) {
    int i = (bid - 1024) * 256 + tid;
    float4 v = ((const float4*)P.hidden0)[i];
    ushort4 o;
    o.x = f2bf(v.x); o.y = f2bf(v.y); o.z = f2bf(v.z); o.w = f2bf(v.w);
    ((ushort4*)P.hball)[i] = o;
  } else if (bid < 1552) {
    int j = bid - 1040;
    tcast_job(P.Wk_c, P.WkcT, 1024, 512, 1024, j & 15, j >> 4, SCW, tid, tb);
  } else if (bid < 1712) {
    int j = bid - 1552;
    tcast_job(P.Wk_u, P.WkuT, 300, 512, 320, j % 16, j / 16, SCW, tid, tb);
  } else if (bid < 1968) {
    int j = bid - 1712;
    tcast_job(P.Wq_c, P.WqcuT, 512, 512, 512, j & 15, j >> 4, SCW, tid, tb);
  } else if (bid < 2224) {
    int j = bid - 1968;
    tcast_job(P.Wq_u, P.WqcuT + 512ull * 512, 512, 512, 512, j & 15, j >> 4, SCW, tid, tb);
  } else if (bid < 3296) {
    int j = bid - 2224;
    tcast_job(P.Wc, P.WcT, 2136, 512, 2144, j % 16, j / 16, 1.f, tid, tb);
  } else if (bid < 3680) {
    int row = (bid - 3296) * 4 + (tid >> 6), k = tid & 63;
    for (int kk = k; kk < 320; kk += 64)
      P.WihT[(size_t)row * 320 + kk] =
          (kk < 300) ? f2bf(P.W_ih[(size_t)row * 300 + kk]) : (us)0;
  } else if (bid < 4064) {
    int job = (bid - 3680) * 4 + (tid >> 6), l = tid & 63;
    int q = job / 192, rem = job - q * 192, lt2 = rem >> 4, kt = rem & 15;
    int localrow = lt2 * 16 + (l & 15);
    int g = localrow >> 6, jj = localrow & 63;
    const float* src =
        P.W_hh + (size_t)(g * 512 + q * 64 + jj) * 512 + kt * 32 + (l >> 4) * 8;
    us* dst = P.WhhF + (((size_t)(q * 12 + lt2) * 16 + kt) * 64 + l) * 8;
#pragma unroll
    for (int i = 0; i < 8; ++i) dst[i] = f2bf(src[i]);
  } else if (bid < 4320) {
    int r = (bid - 4064) * 4 + (tid >> 6), k = tid & 63;
    int t = r >> 5, b = r & 31;
    int tok = (t == 0) ? 1 : P.tgt[b * 32 + (t - 1)];
    const float* src = P.W_embed + (size_t)tok * 300;
    for (int kk = k; kk < 320; kk += 64)
      P.xe[(size_t)r * 320 + kk] = (kk < 300) ? f2bf(src[kk]) : (us)0;
  } else {
    int row = (bid - 4320) * 4 + (tid >> 6), k = tid & 63;
    int tok = P.sv[row];
    const float* src = P.W_embed + (size_t)tok * 300;
    for (int kk = k; kk < 320; kk += 64)
      P.uve[(size_t)row * 320 + kk] = (kk < 300) ? f2bf(src[kk]) : (us)0;
  }
}

// fallback-only transposes
__global__ __launch_bounds__(256) void k_tcastX(const float* __restrict__ src0,
                                                us* __restrict__ dst0,
                                                int R, int C, int Rpad,
                                                size_t srcB, size_t dstB) {
  __shared__ float tile[32 * 33];
  const float* src = src0 + (size_t)blockIdx.z * srcB;
  us* dst = dst0 + (size_t)blockIdx.z * dstB;
  tcast_job(src, dst, R, C, Rpad, blockIdx.x, blockIdx.y, 1.f, threadIdx.x, tile);
}
__global__ __launch_bounds__(256) void k_tcastXb(const us* __restrict__ src0,
                                                 us* __restrict__ dst0,
                                                 int R, int C, int Rpad,
                                                 size_t srcB, size_t dstB) {
  __shared__ us tile[32][33];
  const us* src = src0 + (size_t)blockIdx.z * srcB;
  us* dst = dst0 + (size_t)blockIdx.z * dstB;
  int c0 = blockIdx.x * 32, r0 = blockIdx.y * 32;
  int tx = threadIdx.x & 31, ty = threadIdx.x >> 5;
#pragma unroll
  for (int i = 0; i < 4; ++i) {
    int r = r0 + ty + i * 8, c = c0 + tx;
    tile[ty + i * 8][tx] = (r < R && c < C) ? src[(size_t)r * C + c] : (us)0;
  }
  __syncthreads();
#pragma unroll
  for (int i = 0; i < 4; ++i) {
    int c = c0 + ty + i * 8, rr = r0 + tx;
    if (c < C && rr < Rpad) dst[(size_t)c * Rpad + rr] = tile[tx][ty + i * 8];
  }
}

// --------------------------- big MFMA GEMM (reg-staged) --------------------
// NM=true: N-major block order (mt = bx&3, nt = bx>>2) -> 4 consecutive
// blocks share one B-tile (L2 reuse). Requires M == 1024.
// MODE 0: out bf16 = A@B + bscale*bias
// MODE 1: out fp32 exp -> outF[(r&31)*32+(r>>5)][c] of [1024][50200] + rowsum
// MODE 3: out bf16 exp -> outB (same row mapping, stride 50200) + rowsum,
//         LDS-bounced coalesced stores
template <int MODE, bool NM = false>
__global__ __launch_bounds__(512) void gemm_bt(const us* __restrict__ A,
                                               const us* __restrict__ BT,
                                               int M, int N, int K, int Ntiles,
                                               const float* __restrict__ bias,
                                               float bscale,
                                               us* __restrict__ outB,
                                               float* __restrict__ outF,
                                               float* __restrict__ rowsum) {
  __shared__ us sh[12288];
  __shared__ float rs[256];
  us* As = sh;
  us* Bs = sh + 8192;
  const int tid = threadIdx.x;
  const int lane = tid & 63, wid = tid >> 6;
  const int wr = wid >> 1, wc = wid & 1;
  const int bx = blockIdx.x;
  int mt, nt;
  if (NM) { mt = bx & 3; nt = bx >> 2; }
  else { mt = bx / Ntiles; nt = bx - mt * Ntiles; }
  const int m0 = mt * 256, n0 = nt * 128;
  f32x4 acc[4][4] = {};
  for (int kk = 0; kk < K; kk += 32) {
    uint4 av0, av1, bv;
    {
      int c = tid, row = c >> 2, c8 = (c & 3) * 8;
      av0 = *(const uint4*)(A + (size_t)(m0 + row) * K + kk + c8);
      c = tid + 512; row = c >> 2; c8 = (c & 3) * 8;
      av1 = *(const uint4*)(A + (size_t)(m0 + row) * K + kk + c8);
      c = tid; row = c >> 2; c8 = (c & 3) * 8;
      int nr = n0 + row; if (nr > N - 1) nr = N - 1;
      bv = *(const uint4*)(BT + (size_t)nr * K + kk + c8);
    }
    __syncthreads();
    ((uint4*)As)[tid] = av0;
    ((uint4*)As)[tid + 512] = av1;
    ((uint4*)Bs)[tid] = bv;
    __syncthreads();
    short8 af[4], bfr[4];
#pragma unroll
    for (int m = 0; m < 4; ++m)
      af[m] = *(const short8*)(As + (wr * 64 + m * 16 + (lane & 15)) * 32 + (lane >> 4) * 8);
#pragma unroll
    for (int n = 0; n < 4; ++n)
      bfr[n] = *(const short8*)(Bs + (wc * 64 + n * 16 + (lane & 15)) * 32 + (lane >> 4) * 8);
#pragma unroll
    for (int m = 0; m < 4; ++m)
#pragma unroll
      for (int n = 0; n < 4; ++n)
        acc[m][n] = __builtin_amdgcn_mfma_f32_16x16x32_bf16(af[m], bfr[n], acc[m][n], 0, 0, 0);
  }
  if (MODE == 0) {
#pragma unroll
    for (int m = 0; m < 4; ++m)
#pragma unroll
      for (int n = 0; n < 4; ++n)
#pragma unroll
        for (int reg = 0; reg < 4; ++reg) {
          int r = m0 + wr * 64 + m * 16 + (lane >> 4) * 4 + reg;
          int c = n0 + wc * 64 + n * 16 + (lane & 15);
          outB[(size_t)r * N + c] = f2bf(acc[m][n][reg] + bscale * bias[c]);
        }
  } else {
    if (tid < 256) rs[tid] = 0.f;
    __syncthreads();
#pragma unroll
    for (int m = 0; m < 4; ++m) {
#pragma unroll
      for (int reg = 0; reg < 4; ++reg) {
        int rloc = wr * 64 + m * 16 + (lane >> 4) * 4 + reg;
        float s = 0.f;
#pragma unroll
        for (int n = 0; n < 4; ++n) {
          int c = n0 + wc * 64 + n * 16 + (lane & 15);
          float e = (c < N) ? __expf(acc[m][n][reg]) : 0.f;
          if (MODE == 3) {
            int lrow = wr * 16 + (lane >> 4) * 4 + reg;
            int lcol = wc * 64 + n * 16 + (lane & 15);
            sh[lrow * 136 + lcol] = f2bf(e);
          } else if (c < N) {
            int r = m0 + rloc;
            size_t obase = (size_t)((r & 31) * 32 + (r >> 5)) * 50200;
            outF[obase + c] = e;
          }
          s += e;
        }
        s += __shfl_xor(s, 1, 64); s += __shfl_xor(s, 2, 64);
        s += __shfl_xor(s, 4, 64); s += __shfl_xor(s, 8, 64);
        if ((lane & 15) == 0) atomicAdd(&rs[rloc], s);
      }
      if (MODE == 3) {
        __syncthreads();
#pragma unroll
        for (int k2 = 0; k2 < 2; ++k2) {
          int idx = tid + k2 * 512;
          int l = idx >> 4, u = idx & 15;
          int r = m0 + (l >> 4) * 64 + m * 16 + (l & 15);
          size_t obase = (size_t)((r & 31) * 32 + (r >> 5)) * 50200;
          *(uint4*)(outB + obase + n0 + u * 8) = *(const uint4*)(sh + l * 136 + u * 8);
        }
        __syncthreads();
      }
    }
    __syncthreads();
    if (tid < 256) atomicAdd(&rowsum[m0 + tid], rs[tid]);
  }
}

// --------------------------- medium MFMA GEMM (BM=64, BN=128) --------------
template <int MODE>
__global__ __launch_bounds__(256) void gemm_med(const us* __restrict__ A,
                                                const us* __restrict__ BT,
                                                int M, int N, int K, int Ntiles,
                                                const float* __restrict__ bias,
                                                float bscale,
                                                us* __restrict__ outB) {
  __shared__ us As[64 * 32];
  __shared__ us Bs[128 * 32];
  const int tid = threadIdx.x, lane = tid & 63, w = tid >> 6;
  const int bx = blockIdx.x;
  const int mt = bx / Ntiles, nt = bx - mt * Ntiles;
  const int m0 = mt * 64, n0 = nt * 128;
  f32x4 acc[4][2] = {};
  for (int kk = 0; kk < K; kk += 32) {
    uint4 av, bv0, bv1;
    av = *(const uint4*)(A + (size_t)(m0 + (tid >> 2)) * K + kk + (tid & 3) * 8);
    {
      int i0 = tid * 2, i1 = tid * 2 + 1;
      bv0 = *(const uint4*)(BT + (size_t)(n0 + (i0 >> 2)) * K + kk + (i0 & 3) * 8);
      bv1 = *(const uint4*)(BT + (size_t)(n0 + (i1 >> 2)) * K + kk + (i1 & 3) * 8);
    }
    __syncthreads();
    ((uint4*)As)[tid] = av;
    ((uint4*)Bs)[tid * 2] = bv0;
    ((uint4*)Bs)[tid * 2 + 1] = bv1;
    __syncthreads();
    short8 af[4], bf0, bf1;
#pragma unroll
    for (int m = 0; m < 4; ++m)
      af[m] = *(const short8*)(As + (m * 16 + (lane & 15)) * 32 + (lane >> 4) * 8);
    bf0 = *(const short8*)(Bs + ((w * 2 + 0) * 16 + (lane & 15)) * 32 + (lane >> 4) * 8);
    bf1 = *(const short8*)(Bs + ((w * 2 + 1) * 16 + (lane & 15)) * 32 + (lane >> 4) * 8);
#pragma unroll
    for (int m = 0; m < 4; ++m) {
      acc[m][0] = __builtin_amdgcn_mfma_f32_16x16x32_bf16(af[m], bf0, acc[m][0], 0, 0, 0);
      acc[m][1] = __builtin_amdgcn_mfma_f32_16x16x32_bf16(af[m], bf1, acc[m][1], 0, 0, 0);
    }
  }
#pragma unroll
  for (int m = 0; m < 4; ++m)
#pragma unroll
    for (int q = 0; q < 2; ++q)
#pragma unroll
      for (int reg = 0; reg < 4; ++reg) {
        int r = m0 + m * 16 + (lane >> 4) * 4 + reg;
        int c = n0 + (w * 2 + q) * 16 + (lane & 15);
        float v = acc[m][q][reg];
        if (MODE == 0) v += bscale * bias[c];
        else v = ftanh_fast(v);
        outB[(size_t)r * N + c] = f2bf(v);
      }
}

// --------------------------- fat kernel (r7 classes) -----------------------
// 0-7 GRU | 8-207 pkc | 208-307 pku | 308-829 WT | 830-1107 encTp |
// 1108-1154 uveTp. 58KB pool, 2 blocks/CU.
struct FP {
  const us* frag; const us* gib; const float* bhh; const float* hidden0;
  us* hball; int* arrive;
  const us* encb; const us* WkcT; const float* bkc; us* pkc;
  const us* uve; const us* WkuT; const float* bku; us* pku;
  const float* Wgen; us* WT;
  const float* enc; us* encTp;
  us* uveTp;
};

__device__ void gru_body(const FP& P, int q, int tid, char* pool) {
  us* hs = (us*)pool;                  // 32 KB
  float* gh = (float*)(pool + 32768);  // 25344 B
  const int lane = tid & 63, w = tid >> 6;
  short8 bfr[16];
  {
    const us* fb = P.frag + (((size_t)(q * 12 + w) * 16) * 64 + lane) * 8;
#pragma unroll
    for (int kt = 0; kt < 16; ++kt) bfr[kt] = *(const short8*)(fb + (size_t)kt * 512);
  }
  float hprev[3], bh0[3], bh1[3], bh2[3];
#pragma unroll
  for (int s = 0; s < 3; ++s) {
    int i = tid + s * 768;
    if (i < 2048) {
      int b = i >> 6, jj = i & 63, j = q * 64 + jj;
      hprev[s] = P.hidden0[b * 512 + j];
      bh0[s] = P.bhh[j]; bh1[s] = P.bhh[512 + j]; bh2[s] = P.bhh[1024 + j];
    }
  }
  const int sw = (lane & 7) << 3;
  for (int t = 0; t < 32; ++t) {
    // prefetch this step's gi gates into regs (gib is launch-constant; loads
    // fly during the flag spin)
    float gi0[3], gi1[3], gi2[3];
#pragma unroll
    for (int s = 0; s < 3; ++s) {
      int i = tid + s * 768;
      if (i < 2048) {
        int b = i >> 6, jj = i & 63, j = q * 64 + jj;
        size_t gbase = (size_t)(t * 32 + b) * 1536;
        gi0[s] = bf2f(P.gib[gbase + j]);
        gi1[s] = bf2f(P.gib[gbase + 512 + j]);
        gi2[s] = bf2f(P.gib[gbase + 1024 + j]);
      }
    }
    if (t > 0) {
      if (tid == 0) {
        while (__hip_atomic_load(P.arrive + (t - 1), __ATOMIC_ACQUIRE,
                                 __HIP_MEMORY_SCOPE_AGENT) < 8) {
          __builtin_amdgcn_s_sleep(1);
        }
      }
      __syncthreads();
    }
    const us* hp = P.hball + (size_t)t * 16384;
    for (int i = tid; i < 2048; i += 768)
      ((uint4*)hs)[i ^ ((i >> 6) & 7)] = *(const uint4*)(hp + i * 8);
    __syncthreads();
    f32x4 acc0 = {}, acc1 = {};
#pragma unroll
    for (int kt = 0; kt < 16; ++kt) {
      int base0 = ((lane & 15) * 512 + kt * 32 + (lane >> 4) * 8) ^ sw;
      int base1 = (((lane & 15) + 16) * 512 + kt * 32 + (lane >> 4) * 8) ^ sw;
      short8 a0 = *(const short8*)(hs + base0);
      short8 a1 = *(const short8*)(hs + base1);
      acc0 = __builtin_amdgcn_mfma_f32_16x16x32_bf16(a0, bfr[kt], acc0, 0, 0, 0);
      acc1 = __builtin_amdgcn_mfma_f32_16x16x32_bf16(a1, bfr[kt], acc1, 0, 0, 0);
    }
    {
      int col = w * 16 + (lane & 15);
#pragma unroll
      for (int reg = 0; reg < 4; ++reg) {
        gh[col * 33 + ((lane >> 4) * 4 + reg)] = acc0[reg];
        gh[col * 33 + (16 + (lane >> 4) * 4 + reg)] = acc1[reg];
      }
    }
    __syncthreads();
    us* hbn = P.hball + (size_t)(t + 1) * 16384;
#pragma unroll
    for (int s = 0; s < 3; ++s) {
      int i = tid + s * 768;
      if (i < 2048) {
        int b = i >> 6, jj = i & 63, j = q * 64 + jj;
        float g0 = gh[jj * 33 + b] + bh0[s];
        float g1 = gh[(64 + jj) * 33 + b] + bh1[s];
        float g2 = gh[(128 + jj) * 33 + b] + bh2[s];
        float r_ = fsigmoid(gi0[s] + g0);
        float z_ = fsigmoid(gi1[s] + g1);
        float n_ = ftanh(gi2[s] + r_ * g2);
        float hv = (1.f - z_) * n_ + z_ * hprev[s];
        hprev[s] = hv;
        hbn[b * 512 + j] = f2bf(hv);
      }
    }
    __syncthreads();  // drains h stores
    if (tid == 0)
      __hip_atomic_fetch_add(P.arrive + t, 1, __ATOMIC_RELEASE,
                             __HIP_MEMORY_SCOPE_AGENT);
  }
}

// BM=256 BN=128 tile; active tid<512, all threads hit barriers.
__device__ void gemm0_body(const us* A, const us* BT, int N, int K,
                           int mt, int nt, const float* bias, float bscale,
                           us* outB, int tid, char* pool) {
  us* As = (us*)pool;
  us* Bs = (us*)(pool + 16384);
  const bool act = tid < 512;
  const int lane = tid & 63, wid = (tid >> 6) & 7;
  const int wr = wid >> 1, wc = wid & 1;
  const int m0 = mt * 256, n0 = nt * 128;
  f32x4 acc[4][4] = {};
  for (int kk = 0; kk < K; kk += 32) {
    uint4 av0 = {0, 0, 0, 0}, av1 = {0, 0, 0, 0}, bv = {0, 0, 0, 0};
    if (act) {
      int c = tid, row = c >> 2, c8 = (c & 3) * 8;
      av0 = *(const uint4*)(A + (size_t)(m0 + row) * K + kk + c8);
      av1 = *(const uint4*)(A + (size_t)(m0 + 128 + row) * K + kk + c8);
      int nr = n0 + row; if (nr > N - 1) nr = N - 1;
      bv = *(const uint4*)(BT + (size_t)nr * K + kk + c8);
    }
    __syncthreads();
    if (act) {
      ((uint4*)As)[tid] = av0;
      ((uint4*)As)[tid + 512] = av1;
      ((uint4*)Bs)[tid] = bv;
    }
    __syncthreads();
    if (act) {
      short8 af[4], bfr[4];
#pragma unroll
      for (int m = 0; m < 4; ++m)
        af[m] = *(const short8*)(As + (wr * 64 + m * 16 + (lane & 15)) * 32 + (lane >> 4) * 8);
#pragma unroll
      for (int n = 0; n < 4; ++n)
        bfr[n] = *(const short8*)(Bs + (wc * 64 + n * 16 + (lane & 15)) * 32 + (lane >> 4) * 8);
#pragma unroll
      for (int m = 0; m < 4; ++m)
#pragma unroll
        for (int n = 0; n < 4; ++n)
          acc[m][n] = __builtin_amdgcn_mfma_f32_16x16x32_bf16(af[m], bfr[n], acc[m][n], 0, 0, 0);
    }
  }
  if (act) {
#pragma unroll
    for (int m = 0; m < 4; ++m)
#pragma unroll
      for (int n = 0; n < 4; ++n)
#pragma unroll
        for (int reg = 0; reg < 4; ++reg) {
          int r = m0 + wr * 64 + m * 16 + (lane >> 4) * 4 + reg;
          int c = n0 + wc * 64 + n * 16 + (lane & 15);
          outB[(size_t)r * N + c] = f2bf(acc[m][n][reg] + bscale * bias[c]);
        }
  }
}

__global__ __launch_bounds__(768, 1) void k_fat(FP P) {
  __shared__ char pool[58368];
  const int bid = blockIdx.x, tid = threadIdx.x;
  if (bid < 8) { gru_body(P, bid, tid, pool); return; }
  if (bid < 208) {  // pkc: 50 mt x 4 nt
    int j = bid - 8;
    gemm0_body(P.encb, P.WkcT, 512, 1024, j >> 2, j & 3, P.bkc, SCW, P.pkc, tid, pool);
    return;
  }
  if (bid < 308) {  // pku: 25 mt x 4 nt
    int j = bid - 208;
    gemm0_body(P.uve, P.WkuT, 512, 320, j >> 2, j & 3, P.bku, SCW, P.pku, tid, pool);
    return;
  }
  // transpose classes: 3 x 256-thread groups, 16 iterations
  const int g = tid >> 8, lt = tid & 255;
  const int tx = lt & 31, ty = lt >> 5;
  float* tb = (float*)(pool + g * 4224);
  if (bid < 830) {  // WT: 25008 subjobs, stride 1566
    int base = (bid - 308) * 3 + g;
    for (int it = 0; it < 16; ++it) {
      int sub = base + it * 1566;
      bool valid = sub < 25008;
      int x = valid ? sub % 1563 : 0, y = valid ? sub / 1563 : 0;
      int c0 = x * 32, r0 = y * 32;
      if (valid) {
#pragma unroll
        for (int i = 0; i < 4; ++i) {
          int r = r0 + ty + i * 8, c = c0 + tx;
          tb[(ty + i * 8) * 33 + tx] =
              (c < 50000) ? P.Wgen[(size_t)r * 50000 + c] : 0.f;
        }
      }
      __syncthreads();
      if (valid) {
#pragma unroll
        for (int i = 0; i < 4; ++i) {
          int c = c0 + ty + i * 8;
          if (c < 50000)
            P.WT[(size_t)c * 512 + r0 + tx] = f2bf(tb[tx * 33 + ty + i * 8]);
        }
      }
      __syncthreads();
    }
    return;
  }
  if (bid < 1108) {  // encTp: 13312 subjobs, stride 834
    int base = (bid - 830) * 3 + g;
    for (int it = 0; it < 16; ++it) {
      int sub = base + it * 834;
      bool valid = sub < 13312;
      int x = sub & 31, rem = sub >> 5;
      int y = rem % 13, z = rem / 13;
      const float* src = P.enc + (size_t)z * 409600;
      us* dst = P.encTp + (size_t)z * 425984;
      int c0 = x * 32, r0 = y * 32;
      if (valid) {
#pragma unroll
        for (int i = 0; i < 4; ++i) {
          int r = r0 + ty + i * 8, c = c0 + tx;
          tb[(ty + i * 8) * 33 + tx] = (r < 400) ? src[(size_t)r * 1024 + c] : 0.f;
        }
      }
      __syncthreads();
      if (valid) {
#pragma unroll
        for (int i = 0; i < 4; ++i) {
          int c = c0 + ty + i * 8, rr = r0 + tx;
          if (rr < 416) dst[(size_t)c * 416 + rr] = f2bf(tb[tx * 33 + ty + i * 8]);
        }
      }
      __syncthreads();
    }
    return;
  }
  {  // uveTp: 2240 subjobs, stride 141
    us* tbu = (us*)tb;
    int base = (bid - 1108) * 3 + g;
    for (int it = 0; it < 16; ++it) {
      int sub = base + it * 141;
      bool valid = sub < 2240;
      int x = sub % 10, rem = sub / 10;
      int y = rem % 7, z = rem / 7;
      const us* src = P.uve + (size_t)z * 64000;
      us* dst = P.uveTp + (size_t)z * 71680;
      int c0 = x * 32, r0 = y * 32;
      if (valid) {
#pragma unroll
        for (int i = 0; i < 4; ++i) {
          int r = r0 + ty + i * 8, c = c0 + tx;
          tbu[(ty + i * 8) * 33 + tx] = (r < 200) ? src[(size_t)r * 320 + c] : (us)0;
        }
      }
      __syncthreads();
      if (valid) {
#pragma unroll
        for (int i = 0; i < 4; ++i) {
          int c = c0 + ty + i * 8, rr = r0 + tx;
          if (rr < 224) dst[(size_t)c * 224 + rr] = tbu[tx * 33 + ty + i * 8];
        }
      }
      __syncthreads();
    }
  }
}

// --------------------------- batched scores --------------------------------
// 2432 blocks: enc 1600 (32 b x 25 s-chunks x 2 t-halves), usr 832 (32x13x2).
__global__ __launch_bounds__(256) void k_scores(const us* __restrict__ Qall,
                                                const us* __restrict__ pkc,
                                                const us* __restrict__ pku,
                                                const float* __restrict__ wec,
                                                const float* __restrict__ bec,
                                                const float* __restrict__ weu,
                                                const float* __restrict__ beu,
                                                const int* __restrict__ src_mask,
                                                float* __restrict__ sc_enc,
                                                float* __restrict__ sc_usr) {
  __shared__ us q[16 * 512];
  const int bid = blockIdx.x;
  const bool enc = bid < 1600;
  int b, s0, th, qoff, S;
  if (enc) {
    b = bid / 50;
    int r = bid % 50;
    s0 = (r >> 1) * 16; th = r & 1; qoff = 0; S = 400;
  } else {
    int j = bid - 1600;
    b = j / 26;
    int r = j % 26;
    s0 = (r >> 1) * 16; th = r & 1; qoff = 512; S = 200;
  }
  for (int i = threadIdx.x; i < 1024; i += 256) {
    int tt = th * 16 + (i >> 6), c8 = (i & 63) * 8;
    ((uint4*)q)[i] = *(const uint4*)(Qall + (size_t)(tt * 32 + b) * 1024 + qoff + c8);
  }
  const int w = threadIdx.x >> 6, lane = threadIdx.x & 63;
  const int d0 = lane * 8;
  const float* we = enc ? wec : weu;
  float wef[8];
  {
    float4 w0 = *(const float4*)(we + d0);
    float4 w1 = *(const float4*)(we + d0 + 4);
    wef[0] = w0.x; wef[1] = w0.y; wef[2] = w0.z; wef[3] = w0.w;
    wef[4] = w1.x; wef[5] = w1.y; wef[6] = w1.z; wef[7] = w1.w;
  }
  const float bias = enc ? bec[0] : beu[0];
  float pkf[4][8];
  int ss[4], validv[4], maskedv[4];
#pragma unroll
  for (int si = 0; si < 4; ++si) {
    int s = s0 + w * 4 + si;
    validv[si] = (s < S);
    int sc = validv[si] ? s : (S - 1);
    ss[si] = sc;
    const us* pk = enc ? pkc + ((size_t)b * 400 + sc) * 512
                       : pku + ((size_t)b * 200 + sc) * 512;
    unpack8(*(const uint4*)(pk + d0), pkf[si]);
    maskedv[si] = enc ? (src_mask[b * 400 + sc] == 0) : 0;
  }
  __syncthreads();
  for (int tl = 0; tl < 16; ++tl) {
    short8 qv = *(const short8*)(q + tl * 512 + d0);
    float qf[8];
#pragma unroll
    for (int d = 0; d < 8; ++d) qf[d] = bf2f((us)qv[d]);
#pragma unroll
    for (int si = 0; si < 4; ++si) {
      float a = 0.f;
#pragma unroll
      for (int d = 0; d < 8; ++d) {
        float x = qf[d] + pkf[si][d];  // = SCW*(q+pk), SCW < 0
        float u = exp2f(-fabsf(x));
        float r2v = (1.f - u) * __builtin_amdgcn_rcpf(1.f + u);
        a = fmaf(copysignf(r2v, -x), wef[d], a);
      }
#pragma unroll
      for (int m = 1; m < 64; m <<= 1) a += __shfl_xor(a, m, 64);
      if (lane == 0 && validv[si]) {
        int t = th * 16 + tl;
        float v = a + bias;
        if (enc) sc_enc[(size_t)(t * 32 + b) * 400 + ss[si]] = maskedv[si] ? -1e9f : v;
        else sc_usr[(size_t)(t * 32 + b) * 200 + ss[si]] = v;
      }
    }
  }
}

// --------------------------- softmax + cat + gate-h ------------------------
__device__ __forceinline__ float bmax256(float v, float* r4, int tid) {
#pragma unroll
  for (int m = 1; m < 64; m <<= 1) v = fmaxf(v, __shfl_xor(v, m, 64));
  if ((tid & 63) == 0) r4[tid >> 6] = v;
  __syncthreads();
  float x = fmaxf(fmaxf(r4[0], r4[1]), fmaxf(r4[2], r4[3]));
  __syncthreads();
  return x;
}
__device__ __forceinline__ float bsum256(float v, float* r4, int tid) {
#pragma unroll
  for (int m = 1; m < 64; m <<= 1) v += __shfl_xor(v, m, 64);
  if ((tid & 63) == 0) r4[tid >> 6] = v;
  __syncthreads();
  float x = r4[0] + r4[1] + r4[2] + r4[3];
  __syncthreads();
  return x;
}

// grid 2432: [0,1024) enc softmax | [1024,2048) usr softmax |
// [2048,2304) cat h/ue (4 rows/blk) | [2304,2432) gate-h (8 rows/blk)
__global__ __launch_bounds__(256) void k_soft2(const float* __restrict__ sc_enc,
                                               const float* __restrict__ sc_usr,
                                               us* __restrict__ AC,
                                               us* __restrict__ AU,
                                               float* __restrict__ aual,
                                               float* __restrict__ cp_acc,
                                               const us* __restrict__ hball,
                                               const float* __restrict__ ue,
                                               const float* __restrict__ Wg,
                                               us* __restrict__ catall) {
  __shared__ float r4[4];
  int bid = blockIdx.x, tid = threadIdx.x;
  if (bid < 1024) {
    int t = bid >> 5, b = bid & 31;
    float v0 = (tid < 400) ? sc_enc[(size_t)bid * 400 + tid] : -3e38f;
    float v1 = (tid + 256 < 400) ? sc_enc[(size_t)bid * 400 + tid + 256] : -3e38f;
    float mx = bmax256(fmaxf(v0, v1), r4, tid);
    float e0 = (tid < 400) ? __expf(v0 - mx) : 0.f;
    float e1 = (tid + 256 < 400) ? __expf(v1 - mx) : 0.f;
    float inv = 1.f / bsum256(e0 + e1, r4, tid);
    us* ACb = AC + (size_t)(b * 32 + t) * 416;
    if (tid < 400) ACb[tid] = f2bf(e0 * inv);
    int s2 = tid + 256;
    if (s2 < 400) ACb[s2] = f2bf(e1 * inv);
    else if (s2 < 416) ACb[s2] = 0;
  } else if (bid < 2048) {
    int rr = bid - 1024;
    int t = rr >> 5, b = rr & 31;
    float v0 = (tid < 200) ? sc_usr[(size_t)rr * 200 + tid] : -3e38f;
    float mx = bmax256(v0, r4, tid);
    float e0 = (tid < 200) ? __expf(v0 - mx) : 0.f;
    float inv = 1.f / bsum256(e0, r4, tid);
    us* AUb = AU + (size_t)(b * 32 + t) * 224;
    if (tid < 200) {
      float a = e0 * inv;
      AUb[tid] = f2bf(a);
      aual[(size_t)rr * 200 + tid] = a;
    } else if (tid < 224) {
      AUb[tid] = 0;
    }
  } else if (bid < 2304) {
    int w = tid >> 6, lane = tid & 63;
    int row = (bid - 2048) * 4 + w;
    int t = row >> 5, b = row & 31;
    us* rowp = catall + (size_t)row * 2144;
    const us* hb = hball + (size_t)(t + 1) * 16384 + b * 512;
    *(uint4*)(rowp + lane * 8) = *(const uint4*)(hb + lane * 8);
    for (int i = lane; i < 308; i += 64)
      rowp[1836 + i] = (i < 300) ? f2bf(ue[b * 300 + i]) : (us)0;
  } else {
    int w = tid >> 6, lane = tid & 63, d0 = lane * 8;
#pragma unroll
    for (int k = 0; k < 2; ++k) {
      int row = (bid - 2304) * 8 + w * 2 + k;
      int t = row >> 5, b = row & 31;
      float hv[8];
      unpack8(*(const uint4*)(hball + (size_t)(t + 1) * 16384 + b * 512 + d0), hv);
      float4 g0 = *(const float4*)(Wg + 1024 + d0);
      float4 g1 = *(const float4*)(Wg + 1024 + d0 + 4);
      float a = hv[0] * g0.x + hv[1] * g0.y + hv[2] * g0.z + hv[3] * g0.w +
                hv[4] * g1.x + hv[5] * g1.y + hv[6] * g1.z + hv[7] * g1.w;
#pragma unroll
      for (int m = 1; m < 64; m <<= 1) a += __shfl_xor(a, m, 64);
      if (lane == 0) atomicAdd(&cp_acc[row], a);
    }
  }
}

// --------------------------- merged ctx GEMM -------------------------------
__device__ void ctx_core(const us* Ab, const us* Bb, const float* Wg,
                         us* catall, float* cp_acc, int b, int N, int Kp,
                         int n0, int catOff, int wgOff, int Nvalid, int tid,
                         us* As, us* Bs, float* gaccs) {
  const int lane = tid & 63, w = tid >> 6;
  if (tid < 32) gaccs[tid] = 0.f;
  f32x4 acc[2][2] = {};
  for (int kk = 0; kk < Kp; kk += 32) {
    uint4 av, bv0, bv1;
    if (tid < 128) av = *(const uint4*)(Ab + (size_t)(tid >> 2) * Kp + kk + (tid & 3) * 8);
    {
      int i0 = tid * 2, row0 = i0 >> 2, c0 = (i0 & 3) * 8;
      int i1 = tid * 2 + 1, row1 = i1 >> 2, c1 = (i1 & 3) * 8;
      int nr0 = n0 + row0; if (nr0 > N - 1) nr0 = N - 1;
      int nr1 = n0 + row1; if (nr1 > N - 1) nr1 = N - 1;
      bv0 = *(const uint4*)(Bb + (size_t)nr0 * Kp + kk + c0);
      bv1 = *(const uint4*)(Bb + (size_t)nr1 * Kp + kk + c1);
    }
    __syncthreads();
    if (tid < 128) ((uint4*)As)[tid] = av;
    ((uint4*)Bs)[tid * 2] = bv0;
    ((uint4*)Bs)[tid * 2 + 1] = bv1;
    __syncthreads();
    short8 a0 = *(const short8*)(As + ((lane & 15)) * 32 + (lane >> 4) * 8);
    short8 a1 = *(const short8*)(As + (16 + (lane & 15)) * 32 + (lane >> 4) * 8);
#pragma unroll
    for (int qq = 0; qq < 2; ++qq) {
      short8 bf_ = *(const short8*)(Bs + ((w * 2 + qq) * 16 + (lane & 15)) * 32 + (lane >> 4) * 8);
      acc[0][qq] = __builtin_amdgcn_mfma_f32_16x16x32_bf16(a0, bf_, acc[0][qq], 0, 0, 0);
      acc[1][qq] = __builtin_amdgcn_mfma_f32_16x16x32_bf16(a1, bf_, acc[1][qq], 0, 0, 0);
    }
  }
#pragma unroll
  for (int mt = 0; mt < 2; ++mt)
#pragma unroll
    for (int qq = 0; qq < 2; ++qq)
#pragma unroll
      for (int reg = 0; reg < 4; ++reg) {
        int t_ = mt * 16 + (lane >> 4) * 4 + reg;
        int c = n0 + (w * 2 + qq) * 16 + (lane & 15);
        if (c < Nvalid) {
          float v = acc[mt][qq][reg];
          catall[(size_t)(t_ * 32 + b) * 2144 + catOff + c] = f2bf(v);
          atomicAdd(&gaccs[t_], v * Wg[wgOff + c]);
        }
      }
  __syncthreads();
  if (tid < 32) atomicAdd(&cp_acc[tid * 32 + b], gaccs[tid]);
}

// grid 352: [0,256) enc ctx | [256,352) usr ctx
__global__ __launch_bounds__(256) void k_ctx2(const us* __restrict__ AC,
                                              const us* __restrict__ encTp,
                                              const us* __restrict__ AU,
                                              const us* __restrict__ uveTp,
                                              const float* __restrict__ Wg,
                                              us* __restrict__ catall,
                                              float* __restrict__ cp_acc) {
  __shared__ us As[32 * 32];
  __shared__ us Bs[128 * 32];
  __shared__ float gaccs[32];
  int bid = blockIdx.x, tid = threadIdx.x;
  if (bid < 256) {
    int b = bid >> 3, nt = bid & 7;
    ctx_core(AC + (size_t)b * 32 * 416, encTp + (size_t)b * 1024 * 416, Wg,
             catall, cp_acc, b, 1024, 416, nt * 128, 512, 0, 1024, tid, As, Bs, gaccs);
  } else {
    int j = bid - 256;
    int b = j / 3, nt = j % 3;
    ctx_core(AU + (size_t)b * 32 * 224, uveTp + (size_t)b * 320 * 224, Wg,
             catall, cp_acc, b, 320, 224, nt * 128, 1536, 1536, 300, tid, As, Bs, gaccs);
  }
}

// --------------------------- finalize --------------------------------------
__global__ __launch_bounds__(256) void k_finalize(float* __restrict__ out,
                                                  const float* __restrict__ rowsum,
                                                  const float* __restrict__ cp_acc,
                                                  const float* __restrict__ bg,
                                                  const float* __restrict__ au_all,
                                                  const int* __restrict__ sv) {
  int r = blockIdx.x, t = threadIdx.x;
  int b = r & 31, tt = r >> 5;
  float cp = fsigmoid(cp_acc[r] + bg[0]);
  float scale = (1.f - cp) / rowsum[r];
  float* base = out + (size_t)(b * 32 + tt) * 50200;
  float4* b4 = (float4*)base;
  for (int i = t; i < 12550; i += 256) {
    if (i < 12500) {
      float4 v = b4[i];
      v.x *= scale; v.y *= scale; v.z *= scale; v.w *= scale;
      b4[i] = v;
    } else {
      b4[i] = make_float4(0.f, 0.f, 0.f, 0.f);
    }
  }
  __syncthreads();
  if (t < 200) {
    int idx = sv[b * 200 + t];
    atomicAdd(base + idx, cp * au_all[(size_t)r * 200 + t]);
  }
}

__global__ __launch_bounds__(256) void k_finalize2(const us* __restrict__ expb,
                                                   const float* __restrict__ rowsum,
                                                   const float* __restrict__ cp_acc,
                                                   const float* __restrict__ bg,
                                                   const float* __restrict__ au_all,
                                                   const int* __restrict__ sv,
                                                   float* __restrict__ out) {
  int r = blockIdx.x, t = threadIdx.x;
  int b = r & 31, tt = r >> 5;
  float cp = fsigmoid(cp_acc[r] + bg[0]);
  float scale = (1.f - cp) / rowsum[r];
  size_t obase = (size_t)(b * 32 + tt) * 50200;
  const uint4* eb = (const uint4*)(expb + obase);
  float4* ob = (float4*)(out + obase);
  for (int i = t; i < 6275; i += 256) {
    float4 o0, o1;
    if (i < 6250) {
      uint4 ev = eb[i];
      o0.x = bf2f((us)(ev.x & 0xffff)) * scale; o0.y = bf2f((us)(ev.x >> 16)) * scale;
      o0.z = bf2f((us)(ev.y & 0xffff)) * scale; o0.w = bf2f((us)(ev.y >> 16)) * scale;
      o1.x = bf2f((us)(ev.z & 0xffff)) * scale; o1.y = bf2f((us)(ev.z >> 16)) * scale;
      o1.z = bf2f((us)(ev.w & 0xffff)) * scale; o1.w = bf2f((us)(ev.w >> 16)) * scale;
    } else {
      o0 = make_float4(0.f, 0.f, 0.f, 0.f);
      o1 = o0;
    }
    ob[i * 2] = o0;
    ob[i * 2 + 1] = o1;
  }
  __syncthreads();
  if (t < 200) {
    int idx = sv[b * 200 + t];
    atomicAdd(out + obase + idx, cp * au_all[(size_t)r * 200 + t]);
  }
}

// ---------------------------------------------------------------------------

extern "C" void kernel_launch(void* const* d_in, const int* in_sizes, int n_in,
                              void* d_out, int out_size, void* d_ws, size_t ws_size,
                              hipStream_t stream) {
  (void)in_sizes; (void)n_in; (void)out_size;
  const float* enc = (const float*)d_in[0];
  const float* hidden0 = (const float*)d_in[1];
  const float* user_embed = (const float*)d_in[2];
  const float* W_embed = (const float*)d_in[3];
  const float* W_ih = (const float*)d_in[4];
  const float* W_hh = (const float*)d_in[5];
  const float* b_ih = (const float*)d_in[6];
  const float* b_hh = (const float*)d_in[7];
  const float* Wk_c = (const float*)d_in[8];
  const float* bk_c = (const float*)d_in[9];
  const float* Wq_c = (const float*)d_in[10];
  const float* bq_c = (const float*)d_in[11];
  const float* we_c = (const float*)d_in[12];
  const float* be_c = (const float*)d_in[13];
  const float* Wk_u = (const float*)d_in[14];
  const float* bk_u = (const float*)d_in[15];
  const float* Wq_u = (const float*)d_in[16];
  const float* bq_u = (const float*)d_in[17];
  const float* we_u = (const float*)d_in[18];
  const float* be_u = (const float*)d_in[19];
  const float* Wc = (const float*)d_in[20];
  const float* Wg = (const float*)d_in[21];
  const float* bg = (const float*)d_in[22];
  const float* Wgen = (const float*)d_in[23];
  const int* src_mask = (const int*)d_in[24];
  const int* tgt = (const int*)d_in[25];
  const int* sv = (const int*)d_in[26];
  float* out = (float*)d_out;

  // ---------------- workspace layout ----------------
  char* base = (char*)d_ws;
  size_t off = 0;
  auto take = [&](size_t bytes) {
    char* p = base + off;
    off += (bytes + 255) & ~(size_t)255;
    return p;
  };
  us* WT = (us*)take(50000ull * 512 * 2);
  char* R0 = take(32ull * 1024 * 416 * 2);  // encb (encTp fallback)
  us* encb = (us*)R0;
  char* RCD = take(12800ull * 512 * 2 + 6400ull * 512 * 2);
  us* pkc = (us*)RCD;
  us* pku = (us*)(RCD + 12800ull * 512 * 2);
  us* AC = (us*)RCD;
  us* AU = (us*)(RCD + 860160);
  float* aual = (float*)(RCD + 860160 + 458752);
  us* catall = (us*)(RCD + 860160 + 458752 + 819200);
  us* chb = (us*)(RCD + 860160 + 458752 + 819200 + 4390912);
  us* uve = (us*)take(6400ull * 320 * 2);
  us* uveTp = (us*)take(32ull * 320 * 224 * 2);
  char* RG = take(2700000);  // WkcT | WihT | xe
  us* WkcT = (us*)RG;
  us* WihT = (us*)(RG + 1048576);
  us* xe = (us*)(RG + 1048576 + 983040);
  us* WkuT = (us*)take(512ull * 320 * 2);
  us* WqcuT = (us*)take(1024ull * 512 * 2);
  us* WcT = (us*)take(512ull * 2144 * 2);
  us* WhhF = (us*)take(1536ull * 512 * 2);
  us* gib = (us*)take(1024ull * 1536 * 2);
  us* hball = (us*)take(33ull * 16384 * 2);
  us* Qall = (us*)take(1024ull * 1024 * 2);
  float* sc_enc = (float*)take(1024ull * 400 * 4);
  float* sc_usr = (float*)take(1024ull * 200 * 4);
  float* bqcu = (float*)take(1024 * 4);
  float* cp_acc = (float*)take(1024 * 4);
  float* rsum = (float*)take(1024 * 4);
  int* arrive = (int*)take(32 * 4);
  size_t expb_bytes = 1024ull * 50200 * 2;
  bool big_ws = (ws_size >= off + expb_bytes + 256);
  us* expb = big_ws ? (us*)take(expb_bytes) : nullptr;
  us* encTp = big_ws ? expb : (us*)R0;

  hipMemcpyAsync(bqcu, bq_c, 512 * 4, hipMemcpyDeviceToDevice, stream);
  hipMemcpyAsync(bqcu + 512, bq_u, 512 * 4, hipMemcpyDeviceToDevice, stream);
  hipMemsetAsync(rsum, 0, 1024 * 4, stream);
  hipMemsetAsync(cp_acc, 0, 1024 * 4, stream);
  hipMemsetAsync(arrive, 0, 32 * 4, stream);

  // ---------------- merged precompute + gib ----------------
  PP pp;
  pp.enc = enc; pp.hidden0 = hidden0; pp.Wk_c = Wk_c; pp.Wk_u = Wk_u;
  pp.Wq_c = Wq_c; pp.Wq_u = Wq_u; pp.Wc = Wc; pp.W_ih = W_ih; pp.W_hh = W_hh;
  pp.W_embed = W_embed; pp.tgt = tgt; pp.sv = sv;
  pp.encb = encb; pp.hball = hball; pp.WkcT = WkcT; pp.WkuT = WkuT;
  pp.WqcuT = WqcuT; pp.WcT = WcT; pp.WihT = WihT; pp.WhhF = WhhF;
  pp.xe = xe; pp.uve = uve;
  k_prep<<<5920, 256, 0, stream>>>(pp);
  gemm_med<0><<<192, 256, 0, stream>>>(xe, WihT, 1024, 1536, 320, 12, b_ih, 1.f, gib);

  FP fp;
  fp.frag = WhhF; fp.gib = gib; fp.bhh = b_hh; fp.hidden0 = hidden0;
  fp.hball = hball; fp.arrive = arrive;
  fp.encb = encb; fp.WkcT = WkcT; fp.bkc = bk_c; fp.pkc = pkc;
  fp.uve = uve; fp.WkuT = WkuT; fp.bku = bk_u; fp.pku = pku;
  fp.Wgen = Wgen; fp.WT = WT; fp.enc = enc; fp.encTp = encTp; fp.uveTp = uveTp;

  if (big_ws) {
    // fat: GRU + pkc/pku GEMMs + WT/encTp/uveTp transposes overlapped
    k_fat<<<1155, 768, 0, stream>>>(fp);
  } else {
    // serial fallback
    k_tcastX<<<dim3(1563, 16, 1), 256, 0, stream>>>(Wgen, WT, 512, 50000, 512, 0, 0);
    gemm_bt<0><<<200, 512, 0, stream>>>(encb, WkcT, 12800, 512, 1024, 4, bk_c, SCW,
                                        pkc, nullptr, nullptr);
    gemm_bt<0><<<100, 512, 0, stream>>>(uve, WkuT, 6400, 512, 320, 4, bk_u, SCW,
                                        pku, nullptr, nullptr);
    k_tcastX<<<dim3(32, 13, 32), 256, 0, stream>>>(enc, encTp, 400, 1024, 416,
                                                   400ull * 1024, 1024ull * 416);
    k_tcastXb<<<dim3(10, 7, 32), 256, 0, stream>>>(uve, uveTp, 200, 320, 224,
                                                   200ull * 320, 320ull * 224);
    k_fat<<<8, 768, 0, stream>>>(fp);  // GRU only
  }

  // ---------------- batched attention + output ----------------
  gemm_med<0><<<128, 256, 0, stream>>>(hball + 16384, WqcuT, 1024, 1024, 512, 8,
                                       bqcu, SCW, Qall);
  k_scores<<<2432, 256, 0, stream>>>(Qall, pkc, pku, we_c, be_c, we_u, be_u,
                                     src_mask, sc_enc, sc_usr);
  k_soft2<<<2432, 256, 0, stream>>>(sc_enc, sc_usr, AC, AU, aual, cp_acc,
                                    hball, user_embed, Wg, catall);
  k_ctx2<<<352, 256, 0, stream>>>(AC, encTp, AU, uveTp, Wg, catall, cp_acc);
  gemm_med<2><<<64, 256, 0, stream>>>(catall, WcT, 1024, 512, 2144, 4, nullptr,
                                      1.f, chb);
  if (big_ws) {
    gemm_bt<3, true><<<4 * 391, 512, 0, stream>>>(chb, WT, 1024, 50000, 512, 391,
                                                  nullptr, 1.f, expb, nullptr, rsum);
    k_finalize2<<<1024, 256, 0, stream>>>(expb, rsum, cp_acc, bg, aual, sv, out);
  } else {
    gemm_bt<1, true><<<4 * 391, 512, 0, stream>>>(chb, WT, 1024, 50000, 512, 391,
                                                  nullptr, 1.f, nullptr, out, rsum);
    k_finalize<<<1024, 256, 0, stream>>>(out, rsum, cp_acc, bg, aual, sv);
  }
}